// Round 1
// 3263.061 us; speedup vs baseline: 1.1858x; 1.1858x over previous
//
#include <hip/hip_runtime.h>
#include <hip/hip_bf16.h>

typedef __hip_bfloat16 bf16;

#define N_  100000
#define E_  400000
#define EBI 400000
#define G_  2048

static __device__ __forceinline__ float b2f(bf16 v){ return __bfloat162float(v); }
static __device__ __forceinline__ bf16  f2b(float v){ return __float2bfloat16(v); }

template<typename T> static __device__ __forceinline__ float ldv(const void* p, size_t i){
  return (float)((const T*)p)[i];
}
template<typename T> static __device__ __forceinline__ void stv(void* p, size_t i, float v){
  ((T*)p)[i] = (T)v;
}

// ---------------- dtype probe: even-index bf16 reads of x_h ----------------
// bf16 N(0,1): |v| in (1e-3,16) for ~99.6% of elements. f32 read as bf16:
// even halfwords are mantissa fragments, ~6% in range.
__global__ void k_detect(const void* x, int* flag){
  __shared__ int cnt;
  if(threadIdx.x==0) cnt=0;
  __syncthreads();
  float v = fabsf(b2f(((const bf16*)x)[(size_t)threadIdx.x*2]));
  if(v>1e-3f && v<16.f) atomicAdd(&cnt,1);
  __syncthreads();
  if(threadIdx.x==0) *flag = (cnt<128) ? 1 : 0;   // 1 = external tensors are f32
}

// ---------------- combined attention vectors ----------------
template<typename TE>
static __device__ void combine_body(int idx,
    const void* W_fc,const void* a_s_fc,const void* a_d_fc,
    const void* W_e,const void* a_e,
    const void* W_i,const void* a_s_i,const void* a_d_i,
    const void* W_bs,const void* W_bd,const void* a_s_b,const void* a_d_b,
    float* c_fc_s,float* c_fc_d,float* v_edge,
    float* c_i_s,float* c_i_d,float* c_b_s,float* c_b_d){
  if(idx<384){
    int which=idx>>7; int r=idx&127; int h=r>>6, f=r&63;
    const void* W   = (which==2)? W_e : W_fc;
    const void* att = (which==0)? a_s_fc : (which==1)? a_d_fc : a_e;
    float acc=0.f;
    for(int c=0;c<64;c++) acc += ldv<TE>(W,(size_t)(h*64+c)*64+f)*ldv<TE>(att,h*64+c);
    ((which==0)? c_fc_s : (which==1)? c_fc_d : v_edge)[r]=acc;
  } else if(idx<1408){
    int t=idx-384; int which=t>>8; int r=t&255; int h=r>>7, f=r&127;
    const void* W   = (which<=1)? W_i : (which==2)? W_bs : W_bd;
    const void* att = (which==0)? a_s_i : (which==1)? a_d_i : (which==2)? a_s_b : a_d_b;
    float acc=0.f;
    for(int c=0;c<32;c++) acc += ldv<TE>(W,(size_t)(h*32+c)*128+f)*ldv<TE>(att,h*32+c);
    ((which==0)? c_i_s:(which==1)? c_i_d:(which==2)? c_b_s:c_b_d)[r]=acc;
  }
}
__global__ void k_combine(const int* dflag,
    const void* W_fc,const void* a_s_fc,const void* a_d_fc,
    const void* W_e,const void* a_e,
    const void* W_i,const void* a_s_i,const void* a_d_i,
    const void* W_bs,const void* W_bd,const void* a_s_b,const void* a_d_b,
    float* c_fc_s,float* c_fc_d,float* v_edge,
    float* c_i_s,float* c_i_d,float* c_b_s,float* c_b_d){
  int idx = blockIdx.x*blockDim.x + threadIdx.x;
  if(*dflag) combine_body<float>(idx,W_fc,a_s_fc,a_d_fc,W_e,a_e,W_i,a_s_i,a_d_i,W_bs,W_bd,a_s_b,a_d_b,
                                 c_fc_s,c_fc_d,v_edge,c_i_s,c_i_d,c_b_s,c_b_d);
  else       combine_body<bf16 >(idx,W_fc,a_s_fc,a_d_fc,W_e,a_e,W_i,a_s_i,a_d_i,W_bs,W_bd,a_s_b,a_d_b,
                                 c_fc_s,c_fc_d,v_edge,c_i_s,c_i_d,c_b_s,c_b_d);
}

// ---------------- sorted-segment ranges ----------------
__global__ void k_ranges(const int* __restrict__ batch, int n, int* start, int* end){
  int i = blockIdx.x*blockDim.x + threadIdx.x;
  if(i>=n) return;
  int b = batch[i];
  if(i==0 || batch[i-1]!=b) start[b]=i;
  if(i==n-1 || batch[i+1]!=b) end[b]=i+1;
}

// per-graph raw edge_attr column sums + global column sum
template<typename TE>
static __device__ void easum_body(int g,int f,const void* ea,const int* es,const int* ee,
                                  float* gsum,float* gl){
  int s=es[g], e=ee[g];
  float acc=0.f;
  for(int i=s;i<e;i++) acc += ldv<TE>(ea,(size_t)i*64+f);
  gsum[g*64+f]=acc;
  atomicAdd(&gl[f], acc);
}
__global__ void k_graph_easum(const int* dflag, const void* ea, const int* es, const int* ee,
                              float* gsum, float* gl){
  int g=blockIdx.x, f=threadIdx.x;
  if(*dflag) easum_body<float>(g,f,ea,es,ee,gsum,gl);
  else       easum_body<bf16 >(g,f,ea,es,ee,gsum,gl);
}

__global__ void k_loopae(const float* sumea, const float* v_edge, float* loopae, float invE){
  int h = threadIdx.x; if(h>=2) return;
  float acc=0.f;
  for(int f=0; f<64; f++) acc += sumea[f]*v_edge[h*64+f];
  loopae[h] = acc*invE;
}

template<typename TE>
static __device__ void eags_body(int idx,const float* gsum,const int* es,const int* ee,
                                 const void* W_lu,const void* b_lu,float* ea_gs){
  int g=idx>>6, f=idx&63;
  float acc=0.f;
  for(int k=0;k<64;k++) acc += gsum[g*64+k]*ldv<TE>(W_lu,f*64+k);
  float cnt=(float)(ee[g]-es[g]);
  ea_gs[idx]=acc + cnt*ldv<TE>(b_lu,f);
}
__global__ void k_ea_gs(const int* dflag,const float* gsum,const int* es,const int* ee,
                        const void* W_lu,const void* b_lu,float* ea_gs){
  int idx = blockIdx.x*blockDim.x + threadIdx.x;
  if(idx>=G_*64) return;
  if(*dflag) eags_body<float>(idx,gsum,es,ee,W_lu,b_lu,ea_gs);
  else       eags_body<bf16 >(idx,gsum,es,ee,W_lu,b_lu,ea_gs);
}

template<typename TE>
static __device__ void hge_body(int idx,const float* ea_gs,const void* W_re,const void* b_re,float* hge){
  int g=idx>>7, o=idx&127;
  float acc=0.f;
  for(int f=0;f<64;f++) acc += ea_gs[g*64+f]*ldv<TE>(W_re,(size_t)o*64+f);
  acc += ldv<TE>(b_re,o);
  hge[idx]=acc>0.f?acc:0.f;
}
__global__ void k_hge(const int* dflag,const float* ea_gs,const void* W_re,const void* b_re,float* hge){
  int idx = blockIdx.x*blockDim.x + threadIdx.x;
  if(idx>=G_*128) return;
  if(*dflag) hge_body<float>(idx,ea_gs,W_re,b_re,hge);
  else       hge_body<bf16 >(idx,ea_gs,W_re,b_re,hge);
}

// ---------------- generic dense: out[M,O] = act(A[M,K] @ W[O,K]^T + bias) ----------------
template<typename TA,typename TW,typename TO,int K>
static __device__ void dense_body(const void* A,const void* W,const void* bias,
                                  void* out,size_t outOff,int M,int O,int act,float* wt){
  int tid=threadIdx.x;
  for(int i=tid;i<K*O;i+=256){ int o=i/K,k=i%K; wt[k*O+o]=ldv<TW>(W,i); }
  __syncthreads();
  int CG=O>>2; int cg=tid%CG, rg=tid/CG; int RG=256/CG;
  int m0=blockIdx.x*(2*RG)+2*rg;
  if(m0>=M) return;
  bool has1=(m0+1)<M;
  size_t a0=(size_t)m0*K, a1=a0+(has1?K:0);
  float acc0[4]={0,0,0,0}, acc1[4]={0,0,0,0};
  for(int k=0;k<K;k++){
    float x0=ldv<TA>(A,a0+k), x1=ldv<TA>(A,a1+k);
    const float* w=&wt[k*O];
    #pragma unroll
    for(int j=0;j<4;j++){ float wv=w[cg+j*CG]; acc0[j]+=x0*wv; acc1[j]+=x1*wv; }
  }
  for(int r=0;r<2;r++){
    if(m0+r>=M) break;
    float* acc=r?acc1:acc0;
    for(int j=0;j<4;j++){
      int o=cg+j*CG; float v=acc[j];
      if(bias) v+=ldv<TW>(bias,o);
      if(act) v=v>0.f?v:0.f;
      stv<TO>(out,outOff+(size_t)(m0+r)*O+o,v);
    }
  }
}
template<int K>
__global__ __launch_bounds__(256) void k_dense(const int* dflag,int aExt,int outExt,
    const void* A,const void* W,const void* bias,void* out,size_t outOff,int M,int O,int act){
  __shared__ float wt[8192];
  if(*dflag){
    if(aExt){
      if(outExt) dense_body<float,float,float,K>(A,W,bias,out,outOff,M,O,act,wt);
      else       dense_body<float,float,bf16 ,K>(A,W,bias,out,outOff,M,O,act,wt);
    } else {
      dense_body<bf16,float,bf16,K>(A,W,bias,out,outOff,M,O,act,wt);
    }
  } else {
    dense_body<bf16,bf16,bf16,K>(A,W,bias,out,outOff,M,O,act,wt);
  }
}

// per-head transform of stage-A accumulator + bias + ELU, register-tiled GEMM.
// acc is [N][2][64] f32 (row r=2n+h of 64). One head-half per blockIdx.y.
// Block: 64 nodes x 64 cols. LDS stride 68 breaks the stride-64 bank aliasing;
// W columns stored at om=(o>>2)|((o&3)<<4) so the 16 distinct per-instruction
// column reads land on 8 banks (2-way aliasing = free).
__global__ __launch_bounds__(256) void k_headelu(const int* dflag, const float* __restrict__ acc,
    const void* W, const void* bias, bf16* out, int nNodes){
  __shared__ float sA[64*68];
  __shared__ float sW[64*68];
  __shared__ float sB[64];
  const int t = threadIdx.x;
  const int half = blockIdx.y;
  const int n0 = blockIdx.x*64;
  const int f32 = *dflag;
  // stage W half (64x64) with bank remap
  for(int i=t;i<4096;i+=256){
    int o=i>>6, k=i&63;
    float v = f32 ? ((const float*)W)[(size_t)(half*64+o)*64+k]
                  : b2f(((const bf16*)W)[(size_t)(half*64+o)*64+k]);
    int om = (o>>2) | ((o&3)<<4);
    sW[om*68+k] = v;
  }
  if(t<64) sB[t] = f32 ? ((const float*)bias)[half*64+t] : b2f(((const bf16*)bias)[half*64+t]);
  // stage A tile: rows r = 2*(n0+m)+half, m=0..63 (zero-fill past N)
  for(int i=t;i<1024;i+=256){
    int m=i>>4, k4=i&15;
    int n=n0+m;
    float4 v = make_float4(0.f,0.f,0.f,0.f);
    if(n<nNodes) v = *(const float4*)&acc[((size_t)(2*n+half))*64 + k4*4];
    *(float4*)&sA[m*68 + k4*4] = v;
  }
  __syncthreads();
  const int cg = t&15, rg = t>>4;   // thread: rows rg+16i, cols 4cg+j
  float s[4][4];
  #pragma unroll
  for(int i=0;i<4;i++)
    #pragma unroll
    for(int j=0;j<4;j++) s[i][j]=0.f;
  #pragma unroll 4
  for(int k0=0;k0<64;k0+=4){
    float4 a[4], w[4];
    #pragma unroll
    for(int i=0;i<4;i++) a[i] = *(const float4*)&sA[(rg+16*i)*68 + k0];
    #pragma unroll
    for(int j=0;j<4;j++) w[j] = *(const float4*)&sW[(cg+16*j)*68 + k0];  // col 4cg+j -> om cg+16j
    #pragma unroll
    for(int i=0;i<4;i++)
      #pragma unroll
      for(int j=0;j<4;j++)
        s[i][j] += a[i].x*w[j].x + a[i].y*w[j].y + a[i].z*w[j].z + a[i].w*w[j].w;
  }
  #pragma unroll
  for(int i=0;i<4;i++){
    int n = n0 + rg + 16*i;
    if(n>=nNodes) continue;
    union { bf16 h[4]; uint2 u; } pk;
    #pragma unroll
    for(int j=0;j<4;j++){
      float v = s[i][j] + sB[4*cg+j];
      v = v>0.f ? v : expf(v)-1.f;
      pk.h[j] = f2b(v);
    }
    *(uint2*)&out[((size_t)(2*n+half))*64 + 4*cg] = pk.u;
  }
}

// per-node alphas; aExt: X uses external dtype (else always bf16 scratch)
__global__ void k_node_alpha(const int* dflag,int aExt,int K,const void* X,
                             const float* __restrict__ cva,const float* __restrict__ cvb,
                             float* oa,float* ob,int n){
  int i = blockIdx.x*blockDim.x + threadIdx.x;
  if(i>=n) return;
  float a0=0,a1=0,b0=0,b1=0;
  if(aExt && *dflag){
    const float* x=(const float*)X + (size_t)i*K;
    for(int k=0;k<K;k++){ float v=x[k]; a0+=v*cva[k]; a1+=v*cva[K+k]; b0+=v*cvb[k]; b1+=v*cvb[K+k]; }
  } else {
    const bf16* x=(const bf16*)X + (size_t)i*K;
    for(int k=0;k<K;k++){ float v=b2f(x[k]); a0+=v*cva[k]; a1+=v*cva[K+k]; b0+=v*cvb[k]; b1+=v*cvb[K+k]; }
  }
  oa[i*2]=a0; oa[i*2+1]=a1; ob[i*2]=b0; ob[i*2+1]=b1;
}

// edge alpha + softmax-denominator accumulation (logits are O(10); clamp is safety)
__global__ void k_edge_alpha(const int* dflag,
                             const float* __restrict__ asrc,const float* __restrict__ adst,
                             const int* __restrict__ srcI,const int* __restrict__ dstI,
                             int ne,int nloop,
                             const void* eattr,const float* __restrict__ vedge,
                             const float* __restrict__ loopae,
                             float* alpha,float* ssum){
  int e = blockIdx.x*blockDim.x + threadIdx.x;
  if(e>=ne+nloop) return;
  int s,d; float ae0=0.f, ae1=0.f;
  if(e<ne){
    s=srcI[e]; d=dstI[e];
    if(eattr){
      if(*dflag){
        const float* row=(const float*)eattr + (size_t)e*64;
        for(int k=0;k<64;k++){ float v=row[k]; ae0+=v*vedge[k]; ae1+=v*vedge[64+k]; }
      } else {
        const bf16* row=(const bf16*)eattr + (size_t)e*64;
        for(int k=0;k<64;k++){ float v=b2f(row[k]); ae0+=v*vedge[k]; ae1+=v*vedge[64+k]; }
      }
    }
  } else {
    s=d=e-ne;
    if(eattr){ ae0=loopae[0]; ae1=loopae[1]; }
  }
  float l0 = asrc[s*2]  +adst[d*2]  +ae0; l0 = l0>0.f? l0 : 0.2f*l0;
  float l1 = asrc[s*2+1]+adst[d*2+1]+ae1; l1 = l1>0.f? l1 : 0.2f*l1;
  float a0=expf(fminf(l0,50.f)), a1=expf(fminf(l1,50.f));
  alpha[e*2]=a0; alpha[e*2+1]=a1;
  atomicAdd(&ssum[d*2],  a0);
  atomicAdd(&ssum[d*2+1],a1);
}

// stage-A scatter via linearity: acc[d][h][f] += x[src][f]*alpha_h  (x is 64-wide)
__global__ void k_scatterA(const int* dflag, const void* X, const float* __restrict__ alpha,
                           const float* __restrict__ ssum,
                           const int* __restrict__ srcI, const int* __restrict__ dstI,
                           int ne, int nloop, float* out){
  int idx = blockIdx.x*blockDim.x + threadIdx.x;
  int e = idx>>7, ch = idx&127;
  if(e>=ne+nloop) return;
  int s,d;
  if(e<ne){ s=srcI[e]; d=dstI[e]; } else { s=d=e-ne; }
  int h = ch>>6, f = ch&63;
  float w = alpha[e*2+h]/(ssum[d*2+h]+1e-16f);
  float xv = (*dflag)? ((const float*)X)[(size_t)s*64+f] : b2f(((const bf16*)X)[(size_t)s*64+f]);
  atomicAdd(&out[(size_t)d*128+ch], xv*w);
}

// stage-2 weighted scatter: out[dst, colOff+ch] += msg[src,ch]*alpha/(ssum+eps)
__global__ void k_scatter64(const bf16* __restrict__ msg,const float* __restrict__ alpha,
                            const float* __restrict__ ssum,
                            const int* __restrict__ srcI,const int* __restrict__ dstI,
                            int ne,int nloop,float* out,int colOff){
  int idx = blockIdx.x*blockDim.x + threadIdx.x;
  int e = idx>>6, ch = idx&63;
  if(e>=ne+nloop) return;
  int s,d;
  if(e<ne){ s=srcI[e]; d=dstI[e]; } else { s=d=e-ne; }
  int h = ch>>5;
  float w = alpha[e*2+h]/(ssum[d*2+h]+1e-16f);
  atomicAdd(&out[(size_t)d*128+colOff+ch], b2f(msg[(size_t)s*64+ch])*w);
}

__global__ void k_rep_bias(const int* dflag,float* rep,const void* b0,const void* b1,int total){
  int idx = blockIdx.x*blockDim.x + threadIdx.x;
  if(idx>=total) return;
  int f = idx&127;
  float b;
  if(*dflag) b = (f<64)? ((const float*)b0)[f] : ((const float*)b1)[f-64];
  else       b = (f<64)? b2f(((const bf16*)b0)[f]) : b2f(((const bf16*)b1)[f-64]);
  rep[idx] += b;
}

template<typename TE>
static __device__ void zscore_body(int i,const float* rep,const void* W_rel,const void* b_rel,
                                   const void* W_root,float* z,float* score){
  const float* r = rep + (size_t)i*128;
  float zz=0.f, rr=0.f;
  for(int f=0;f<128;f++){ float v=r[f]; zz+=v*ldv<TE>(W_rel,f); rr+=v*ldv<TE>(W_root,f); }
  z[i]=zz; score[i]=rr+ldv<TE>(b_rel,0);
}
__global__ void k_zscore(const int* dflag,const float* __restrict__ rep,
                         const void* W_rel,const void* b_rel,const void* W_root,
                         float* z,float* score,int n){
  int i = blockIdx.x*blockDim.x + threadIdx.x;
  if(i>=n) return;
  if(*dflag) zscore_body<float>(i,rep,W_rel,b_rel,W_root,z,score);
  else       zscore_body<bf16 >(i,rep,W_rel,b_rel,W_root,z,score);
}

__global__ void k_score_scatter(const float* __restrict__ z,const int* __restrict__ srcI,
                                const int* __restrict__ dstI,float* score,int ne){
  int e = blockIdx.x*blockDim.x + threadIdx.x;
  if(e>=ne) return;
  atomicAdd(&score[dstI[e]], z[srcI[e]]);
}

// SAG readout with per-graph max-subtracted softmax
__global__ void k_readout(const int* dflag,const float* __restrict__ rep,const float* __restrict__ score,
                          const int* ns,const int* ne,const float* __restrict__ hge,
                          void* out,size_t outOff){
  int g = blockIdx.x; int tid = threadIdx.x;
  int s = ns[g], e = ne[g];
  __shared__ float red[128];
  float m=-1e30f;
  for(int n=s+tid;n<e;n+=128) m=fmaxf(m,score[n]);
  red[tid]=m; __syncthreads();
  for(int w=64;w>0;w>>=1){ if(tid<w) red[tid]=fmaxf(red[tid],red[tid+w]); __syncthreads(); }
  float M=red[0]; __syncthreads();
  float loc=0.f;
  for(int n=s+tid;n<e;n+=128) loc += expf(score[n]-M);
  red[tid]=loc; __syncthreads();
  for(int w=64;w>0;w>>=1){ if(tid<w) red[tid]+=red[tid+w]; __syncthreads(); }
  float inv = 1.f/(red[0]+1e-16f);
  float acc=0.f;
  for(int n=s;n<e;n++) acc += rep[(size_t)n*128+tid]*expf(score[n]-M);
  float v = acc*inv + hge[g*128+tid];
  if(*dflag) ((float*)out)[outOff+(size_t)g*128+tid]=v;
  else       ((bf16 *)out)[outOff+(size_t)g*128+tid]=f2b(v);
}

// graph LayerNorm (mode='graph') + relu
__global__ void k_ln(const int* dflag,const float* __restrict__ rep,const int* ns,const int* ne,
                     const void* lnw,const void* lnb,void* out,size_t outOff){
  int g = blockIdx.x; int tid = threadIdx.x;
  int s = ns[g], e = ne[g];
  __shared__ float r1[128];
  float sm=0.f, sq=0.f;
  for(int n=s;n<e;n++){ float v=rep[(size_t)n*128+tid]; sm+=v; sq+=v*v; }
  r1[tid]=sm; __syncthreads();
  for(int w=64;w>0;w>>=1){ if(tid<w) r1[tid]+=r1[tid+w]; __syncthreads(); }
  float S = r1[0]; __syncthreads();
  r1[tid]=sq; __syncthreads();
  for(int w=64;w>0;w>>=1){ if(tid<w) r1[tid]+=r1[tid+w]; __syncthreads(); }
  float SQ = r1[0];
  float cnt=(float)(e-s);
  float norm = (cnt>1.f? cnt:1.f)*128.f;
  float mean = S/norm;
  float var = SQ/norm - mean*mean;
  var = var>0.f? var:0.f;
  float inv = rsqrtf(var+1e-5f);
  int f32 = *dflag;
  float wf,bb;
  if(f32){ wf=((const float*)lnw)[tid]; bb=((const float*)lnb)[tid]; }
  else   { wf=b2f(((const bf16*)lnw)[tid]); bb=b2f(((const bf16*)lnb)[tid]); }
  for(int n=s;n<e;n++){
    float v=(rep[(size_t)n*128+tid]-mean)*inv*wf+bb;
    v = v>0.f? v:0.f;
    if(f32) ((float*)out)[outOff+(size_t)n*128+tid]=v;
    else    ((bf16 *)out)[outOff+(size_t)n*128+tid]=f2b(v);
  }
}

extern "C" void kernel_launch(void* const* d_in, const int* in_sizes, int n_in,
                              void* d_out, int out_size, void* d_ws, size_t ws_size,
                              hipStream_t stream) {
  const void* x_h      = d_in[0];
  const void* x_t      = d_in[1];
  const void* eat_h    = d_in[2];
  const void* eat_t    = d_in[3];
  const int*  ei_h     = (const int*)d_in[4];
  const int*  ei_t     = (const int*)d_in[5];
  const int*  bei      = (const int*)d_in[6];
  const int*  batch_h  = (const int*)d_in[7];
  const int*  batch_t  = (const int*)d_in[8];
  const int*  ebat_h   = (const int*)d_in[9];
  const int*  ebat_t   = (const int*)d_in[10];
  const void* W_fc     = d_in[11];
  const void* a_s_fc   = d_in[12];
  const void* a_d_fc   = d_in[13];
  const void* W_e      = d_in[14];
  const void* a_e      = d_in[15];
  const void* b_fc     = d_in[16];
  const void* W_lu     = d_in[17];
  const void* b_lu     = d_in[18];
  const void* W_i      = d_in[19];
  const void* a_s_i    = d_in[20];
  const void* a_d_i    = d_in[21];
  const void* b_intra  = d_in[22];
  const void* W_bs     = d_in[23];
  const void* W_bd     = d_in[24];
  const void* a_s_b    = d_in[25];
  const void* a_d_b    = d_in[26];
  const void* b_inter  = d_in[27];
  const void* W_rel    = d_in[28];
  const void* b_rel    = d_in[29];
  const void* W_root   = d_in[30];
  const void* ln_w     = d_in[31];
  const void* ln_b     = d_in[32];
  const void* W_re     = d_in[33];
  const void* b_re     = d_in[34];

  // output element offsets (elements, in output dtype)
  const size_t o_hx  = 0;
  const size_t o_eah = (size_t)N_*128;                       // 12.8M
  const size_t o_tx  = o_eah + (size_t)E_*64;                // 38.4M
  const size_t o_eat = o_tx  + (size_t)N_*128;               // 51.2M
  const size_t o_hg  = o_eat + (size_t)E_*64;                // 76.8M
  const size_t o_tg  = o_hg  + (size_t)G_*128;

  // ---- d_out as mid-pipeline scratch (every element overwritten at the end) ----
  bf16* eh   = (bf16*)d_out + o_hx;                          // [N,128] bf16, dies before k_ln(h)
  bf16* et   = (bf16*)d_out + o_tx;                          // [N,128] bf16, dies before k_ln(t)
  bf16* msgI_h = (bf16*)d_out + o_eah;                       // 4x [N,64] bf16, die before ea_h dense
  bf16* msgI_t = msgI_h + (size_t)N_*64;
  bf16* msgB_h = msgI_h + (size_t)2*N_*64;
  bf16* msgB_t = msgI_h + (size_t)3*N_*64;
  float* areg  = (float*)((bf16*)d_out + o_eat);             // alphas, die before ea_t dense
  float* alpha1_h  = areg;
  float* alpha1_t  = areg + (size_t)(E_+N_)*2;
  float* alpha2_ih = areg + (size_t)2*(E_+N_)*2;
  float* alpha2_it = areg + (size_t)3*(E_+N_)*2;
  float* alpha2_bt = alpha1_h;   // alias: alpha1 dead before stage-2 bipartite
  float* alpha2_bh = alpha1_t;

  // ---------------- workspace arena (small & critical first) ----------------
  char* p = (char*)d_ws;
  size_t off = 0;
  auto alloc = [&](size_t bytes)->char*{
    char* r = p + off; off += (bytes + 255) & ~(size_t)255; return r;
  };
  int* dflag=(int*)alloc(256);
  int* es_h = (int*)alloc(G_*4); int* ee_h = (int*)alloc(G_*4);
  int* es_t = (int*)alloc(G_*4); int* ee_t = (int*)alloc(G_*4);
  int* ns_h = (int*)alloc(G_*4); int* ne_h = (int*)alloc(G_*4);
  int* ns_t = (int*)alloc(G_*4); int* ne_t = (int*)alloc(G_*4);
  float* sumea_h = (float*)alloc(64*4);
  float* sumea_t = (float*)alloc(64*4);
  float* c_fc_s=(float*)alloc(128*4); float* c_fc_d=(float*)alloc(128*4);
  float* v_edge=(float*)alloc(128*4);
  float* c_i_s=(float*)alloc(256*4);  float* c_i_d=(float*)alloc(256*4);
  float* c_b_s=(float*)alloc(256*4);  float* c_b_d=(float*)alloc(256*4);
  float* lae_h=(float*)alloc(2*4);    float* lae_t=(float*)alloc(2*4);
  float* ssum1_h  = (float*)alloc((size_t)N_*2*4);
  float* ssum1_t  = (float*)alloc((size_t)N_*2*4);
  float* ssum2_ih = (float*)alloc((size_t)N_*2*4);
  float* ssum2_it = (float*)alloc((size_t)N_*2*4);
  float* ssum2_bt = (float*)alloc((size_t)N_*2*4);
  float* ssum2_bh = (float*)alloc((size_t)N_*2*4);
  float* a1s_h=(float*)alloc((size_t)N_*2*4); float* a1d_h=(float*)alloc((size_t)N_*2*4);
  float* a1s_t=(float*)alloc((size_t)N_*2*4); float* a1d_t=(float*)alloc((size_t)N_*2*4);
  float* ais_h=(float*)alloc((size_t)N_*2*4); float* aid_h=(float*)alloc((size_t)N_*2*4);
  float* ais_t=(float*)alloc((size_t)N_*2*4); float* aid_t=(float*)alloc((size_t)N_*2*4);
  float* abs_h=(float*)alloc((size_t)N_*2*4); float* abd_h=(float*)alloc((size_t)N_*2*4);
  float* abs_t=(float*)alloc((size_t)N_*2*4); float* abd_t=(float*)alloc((size_t)N_*2*4);
  float* z_h=(float*)alloc((size_t)N_*4); float* z_t=(float*)alloc((size_t)N_*4);
  float* sc_h=(float*)alloc((size_t)N_*4); float* sc_t=(float*)alloc((size_t)N_*4);
  float* gsum_h=(float*)alloc((size_t)G_*64*4); float* gsum_t=(float*)alloc((size_t)G_*64*4);
  float* eags_h=(float*)alloc((size_t)G_*64*4); float* eags_t=(float*)alloc((size_t)G_*64*4);
  float* hge_h =(float*)alloc((size_t)G_*128*4); float* hge_t =(float*)alloc((size_t)G_*128*4);
  float* C = (float*)alloc((size_t)N_*128*4);   // stage-A acc (h), then (t), then t_rep
  float* D = (float*)alloc((size_t)N_*128*4);   // h_rep
  float* t_rep = C;
  float* h_rep = D;

  auto cdiv=[](long a, long b){ return (int)((a+b-1)/b); };

  // ---------------- phase 0: probe, zero, setup ----------------
  k_detect<<<1,256,0,stream>>>(x_h, dflag);
  hipMemsetAsync(es_h, 0, (size_t)G_*4*8, stream);
  hipMemsetAsync(sumea_h, 0, 512, stream);
  hipMemsetAsync(ssum1_h, 0, (size_t)N_*2*4*6, stream);
  hipMemsetAsync(C, 0, (size_t)N_*128*4*2, stream);          // C + D contiguous

  k_combine<<<6,256,0,stream>>>(dflag, W_fc,a_s_fc,a_d_fc, W_e,a_e, W_i,a_s_i,a_d_i,
                                W_bs,W_bd,a_s_b,a_d_b,
                                c_fc_s,c_fc_d,v_edge,c_i_s,c_i_d,c_b_s,c_b_d);
  k_ranges<<<cdiv(E_,256),256,0,stream>>>(ebat_h, E_, es_h, ee_h);
  k_ranges<<<cdiv(E_,256),256,0,stream>>>(ebat_t, E_, es_t, ee_t);
  k_ranges<<<cdiv(N_,256),256,0,stream>>>(batch_h, N_, ns_h, ne_h);
  k_ranges<<<cdiv(N_,256),256,0,stream>>>(batch_t, N_, ns_t, ne_t);
  k_graph_easum<<<G_,64,0,stream>>>(dflag, eat_h, es_h, ee_h, gsum_h, sumea_h);
  k_graph_easum<<<G_,64,0,stream>>>(dflag, eat_t, es_t, ee_t, gsum_t, sumea_t);
  k_loopae<<<1,64,0,stream>>>(sumea_h, v_edge, lae_h, 1.f/(float)E_);
  k_loopae<<<1,64,0,stream>>>(sumea_t, v_edge, lae_t, 1.f/(float)E_);
  k_ea_gs<<<cdiv(G_*64,256),256,0,stream>>>(dflag, gsum_h, es_h, ee_h, W_lu, b_lu, eags_h);
  k_ea_gs<<<cdiv(G_*64,256),256,0,stream>>>(dflag, gsum_t, es_t, ee_t, W_lu, b_lu, eags_t);
  k_hge<<<cdiv(G_*128,256),256,0,stream>>>(dflag, eags_h, W_re, b_re, hge_h);
  k_hge<<<cdiv(G_*128,256),256,0,stream>>>(dflag, eags_t, W_re, b_re, hge_t);

  // ---------------- stage A: feature GATConv (linearity: aggregate x, then W) ----------------
  k_node_alpha<<<cdiv(N_,256),256,0,stream>>>(dflag,1,64, x_h, c_fc_s, c_fc_d, a1s_h, a1d_h, N_);
  k_node_alpha<<<cdiv(N_,256),256,0,stream>>>(dflag,1,64, x_t, c_fc_s, c_fc_d, a1s_t, a1d_t, N_);
  k_edge_alpha<<<cdiv(E_+N_,256),256,0,stream>>>(dflag, a1s_h, a1d_h, ei_h, ei_h+E_, E_, N_,
                                                 eat_h, v_edge, lae_h, alpha1_h, ssum1_h);
  k_edge_alpha<<<cdiv(E_+N_,256),256,0,stream>>>(dflag, a1s_t, a1d_t, ei_t, ei_t+E_, E_, N_,
                                                 eat_t, v_edge, lae_t, alpha1_t, ssum1_t);
  // h side: acc in C -> eh ; then reuse C for t side
  dim3 ghe((unsigned)cdiv(N_,64), 2);
  k_scatterA<<<cdiv((long)(E_+N_)*128,256),256,0,stream>>>(dflag, x_h, alpha1_h, ssum1_h,
                                                 ei_h, ei_h+E_, E_, N_, C);
  k_headelu<<<ghe,256,0,stream>>>(dflag, C, W_fc, b_fc, eh, N_);
  hipMemsetAsync(C, 0, (size_t)N_*128*4, stream);
  k_scatterA<<<cdiv((long)(E_+N_)*128,256),256,0,stream>>>(dflag, x_t, alpha1_t, ssum1_t,
                                                 ei_t, ei_t+E_, E_, N_, C);
  k_headelu<<<ghe,256,0,stream>>>(dflag, C, W_fc, b_fc, et, N_);

  // ---------------- stage 2: message transforms + per-node alphas ----------------
  k_dense<128><<<cdiv(N_,32),256,0,stream>>>(dflag,0,0, eh, W_i,  nullptr, msgI_h, 0, N_, 64, 0);
  k_dense<128><<<cdiv(N_,32),256,0,stream>>>(dflag,0,0, et, W_i,  nullptr, msgI_t, 0, N_, 64, 0);
  k_dense<128><<<cdiv(N_,32),256,0,stream>>>(dflag,0,0, eh, W_bs, nullptr, msgB_h, 0, N_, 64, 0);
  k_dense<128><<<cdiv(N_,32),256,0,stream>>>(dflag,0,0, et, W_bs, nullptr, msgB_t, 0, N_, 64, 0);
  k_node_alpha<<<cdiv(N_,256),256,0,stream>>>(dflag,0,128, eh, c_i_s, c_i_d, ais_h, aid_h, N_);
  k_node_alpha<<<cdiv(N_,256),256,0,stream>>>(dflag,0,128, et, c_i_s, c_i_d, ais_t, aid_t, N_);
  k_node_alpha<<<cdiv(N_,256),256,0,stream>>>(dflag,0,128, eh, c_b_s, c_b_d, abs_h, abd_h, N_);
  k_node_alpha<<<cdiv(N_,256),256,0,stream>>>(dflag,0,128, et, c_b_s, c_b_d, abs_t, abd_t, N_);
  hipMemsetAsync(C, 0, (size_t)N_*128*4, stream);            // C becomes t_rep (D=h_rep still zero)

  // ---------------- stage 2: GAT aggregation ----------------
  k_edge_alpha<<<cdiv(E_+N_,256),256,0,stream>>>(dflag, ais_h, aid_h, ei_h, ei_h+E_, E_, N_,
                                                 nullptr,nullptr,nullptr, alpha2_ih, ssum2_ih);
  k_edge_alpha<<<cdiv(E_+N_,256),256,0,stream>>>(dflag, ais_t, aid_t, ei_t, ei_t+E_, E_, N_,
                                                 nullptr,nullptr,nullptr, alpha2_it, ssum2_it);
  k_edge_alpha<<<cdiv(EBI+N_,256),256,0,stream>>>(dflag, abs_h, abd_t, bei, bei+EBI, EBI, N_,
                                                 nullptr,nullptr,nullptr, alpha2_bt, ssum2_bt);
  k_edge_alpha<<<cdiv(EBI+N_,256),256,0,stream>>>(dflag, abs_t, abd_h, bei+EBI, bei, EBI, N_,
                                                 nullptr,nullptr,nullptr, alpha2_bh, ssum2_bh);
  k_scatter64<<<cdiv((long)(E_+N_)*64,256),256,0,stream>>>(msgI_h, alpha2_ih, ssum2_ih,
                                                 ei_h, ei_h+E_, E_, N_, h_rep, 0);
  k_scatter64<<<cdiv((long)(E_+N_)*64,256),256,0,stream>>>(msgI_t, alpha2_it, ssum2_it,
                                                 ei_t, ei_t+E_, E_, N_, t_rep, 0);
  k_scatter64<<<cdiv((long)(EBI+N_)*64,256),256,0,stream>>>(msgB_h, alpha2_bt, ssum2_bt,
                                                 bei, bei+EBI, EBI, N_, t_rep, 64);
  k_scatter64<<<cdiv((long)(EBI+N_)*64,256),256,0,stream>>>(msgB_t, alpha2_bh, ssum2_bh,
                                                 bei+EBI, bei, EBI, N_, h_rep, 64);
  k_rep_bias<<<cdiv((long)N_*128,256),256,0,stream>>>(dflag, h_rep, b_intra, b_inter, N_*128);
  k_rep_bias<<<cdiv((long)N_*128,256),256,0,stream>>>(dflag, t_rep, b_intra, b_inter, N_*128);

  // ---------------- readout + LN ----------------
  k_zscore<<<cdiv(N_,256),256,0,stream>>>(dflag, h_rep, W_rel, b_rel, W_root, z_h, sc_h, N_);
  k_zscore<<<cdiv(N_,256),256,0,stream>>>(dflag, t_rep, W_rel, b_rel, W_root, z_t, sc_t, N_);
  k_score_scatter<<<cdiv(E_,256),256,0,stream>>>(z_h, ei_h, ei_h+E_, sc_h, E_);
  k_score_scatter<<<cdiv(E_,256),256,0,stream>>>(z_t, ei_t, ei_t+E_, sc_t, E_);
  k_readout<<<G_,128,0,stream>>>(dflag, h_rep, sc_h, ns_h, ne_h, hge_h, d_out, o_hg);
  k_readout<<<G_,128,0,stream>>>(dflag, t_rep, sc_t, ns_t, ne_t, hge_t, d_out, o_tg);
  k_ln<<<G_,128,0,stream>>>(dflag, h_rep, ns_h, ne_h, ln_w, ln_b, d_out, o_hx);   // overwrites eh
  k_ln<<<G_,128,0,stream>>>(dflag, t_rep, ns_t, ne_t, ln_w, ln_b, d_out, o_tx);   // overwrites et

  // ---------------- final: relu(ea) outputs (overwrite msg/alpha scratch) ----------------
  k_dense<64><<<cdiv(E_,32),256,0,stream>>>(dflag,1,1, eat_h, W_lu, b_lu, d_out, o_eah, E_, 64, 1);
  k_dense<64><<<cdiv(E_,32),256,0,stream>>>(dflag,1,1, eat_t, W_lu, b_lu, d_out, o_eat, E_, 64, 1);

  (void)in_sizes; (void)n_in; (void)out_size; (void)ws_size;
}

// Round 2
// 2297.838 us; speedup vs baseline: 1.6839x; 1.4201x over previous
//
#include <hip/hip_runtime.h>
#include <hip/hip_bf16.h>

typedef __hip_bfloat16 bf16;

#define N_  100000
#define E_  400000
#define EBI 400000
#define G_  2048
#define NP1 (N_+1)
#define SCAN_B 1024
#define SCAN_NB ((N_+SCAN_B-1)/SCAN_B)

static __device__ __forceinline__ float b2f(bf16 v){ return __bfloat162float(v); }
static __device__ __forceinline__ bf16  f2b(float v){ return __float2bfloat16(v); }
static __device__ __forceinline__ float bfu(unsigned int u){
  union{unsigned int i; float f;} x; x.i = u<<16; return x.f;
}

template<typename T> static __device__ __forceinline__ float ldv(const void* p, size_t i){
  return (float)((const T*)p)[i];
}
template<typename T> static __device__ __forceinline__ void stv(void* p, size_t i, float v){
  ((T*)p)[i] = (T)v;
}

// ---------------- dtype probe ----------------
__global__ void k_detect(const void* x, int* flag){
  __shared__ int cnt;
  if(threadIdx.x==0) cnt=0;
  __syncthreads();
  float v = fabsf(b2f(((const bf16*)x)[(size_t)threadIdx.x*2]));
  if(v>1e-3f && v<16.f) atomicAdd(&cnt,1);
  __syncthreads();
  if(threadIdx.x==0) *flag = (cnt<128) ? 1 : 0;   // 1 = external tensors are f32
}

// ---------------- combined attention vectors ----------------
template<typename TE>
static __device__ void combine_body(int idx,
    const void* W_fc,const void* a_s_fc,const void* a_d_fc,
    const void* W_e,const void* a_e,
    const void* W_i,const void* a_s_i,const void* a_d_i,
    const void* W_bs,const void* W_bd,const void* a_s_b,const void* a_d_b,
    float* c_fc_s,float* c_fc_d,float* v_edge,
    float* c_i_s,float* c_i_d,float* c_b_s,float* c_b_d){
  if(idx<384){
    int which=idx>>7; int r=idx&127; int h=r>>6, f=r&63;
    const void* W   = (which==2)? W_e : W_fc;
    const void* att = (which==0)? a_s_fc : (which==1)? a_d_fc : a_e;
    float acc=0.f;
    for(int c=0;c<64;c++) acc += ldv<TE>(W,(size_t)(h*64+c)*64+f)*ldv<TE>(att,h*64+c);
    ((which==0)? c_fc_s : (which==1)? c_fc_d : v_edge)[r]=acc;
  } else if(idx<1408){
    int t=idx-384; int which=t>>8; int r=t&255; int h=r>>7, f=r&127;
    const void* W   = (which<=1)? W_i : (which==2)? W_bs : W_bd;
    const void* att = (which==0)? a_s_i : (which==1)? a_d_i : (which==2)? a_s_b : a_d_b;
    float acc=0.f;
    for(int c=0;c<32;c++) acc += ldv<TE>(W,(size_t)(h*32+c)*128+f)*ldv<TE>(att,h*32+c);
    ((which==0)? c_i_s:(which==1)? c_i_d:(which==2)? c_b_s:c_b_d)[r]=acc;
  }
}
__global__ void k_combine(const int* dflag,
    const void* W_fc,const void* a_s_fc,const void* a_d_fc,
    const void* W_e,const void* a_e,
    const void* W_i,const void* a_s_i,const void* a_d_i,
    const void* W_bs,const void* W_bd,const void* a_s_b,const void* a_d_b,
    float* c_fc_s,float* c_fc_d,float* v_edge,
    float* c_i_s,float* c_i_d,float* c_b_s,float* c_b_d){
  int idx = blockIdx.x*blockDim.x + threadIdx.x;
  if(*dflag) combine_body<float>(idx,W_fc,a_s_fc,a_d_fc,W_e,a_e,W_i,a_s_i,a_d_i,W_bs,W_bd,a_s_b,a_d_b,
                                 c_fc_s,c_fc_d,v_edge,c_i_s,c_i_d,c_b_s,c_b_d);
  else       combine_body<bf16 >(idx,W_fc,a_s_fc,a_d_fc,W_e,a_e,W_i,a_s_i,a_d_i,W_bs,W_bd,a_s_b,a_d_b,
                                 c_fc_s,c_fc_d,v_edge,c_i_s,c_i_d,c_b_s,c_b_d);
}

// ---------------- sorted-segment ranges ----------------
__global__ void k_ranges(const int* __restrict__ batch, int n, int* start, int* end){
  int i = blockIdx.x*blockDim.x + threadIdx.x;
  if(i>=n) return;
  int b = batch[i];
  if(i==0 || batch[i-1]!=b) start[b]=i;
  if(i==n-1 || batch[i+1]!=b) end[b]=i+1;
}

// ---------------- CSR build ----------------
__global__ void k_hist(const int* __restrict__ dst, int ne, int* cnt){
  int e = blockIdx.x*blockDim.x + threadIdx.x;
  if(e<ne) atomicAdd(&cnt[dst[e]],1);
}

__global__ __launch_bounds__(256) void k_scan1(const int* __restrict__ cnt, int* rowptr, int* part){
  int g = blockIdx.y, b = blockIdx.x, t = threadIdx.x;
  const int* c = cnt + (size_t)g*N_;
  int* rp = rowptr + (size_t)g*NP1;
  int i0 = b*SCAN_B + t*4;
  int v[4];
  #pragma unroll
  for(int j=0;j<4;j++){ int i=i0+j; v[j] = (i<N_)? c[i] : 0; }
  int T = v[0]+v[1]+v[2]+v[3];
  __shared__ int sh[256];
  sh[t]=T; __syncthreads();
  int run=T;
  for(int o=1;o<256;o<<=1){
    int add = (t>=o)? sh[t-o] : 0;
    __syncthreads();
    run += add; sh[t]=run;
    __syncthreads();
  }
  int p = run - T;   // exclusive prefix for this thread
  #pragma unroll
  for(int j=0;j<4;j++){ int i=i0+j; if(i<N_) rp[i]=p; p+=v[j]; }
  if(t==255) part[g*SCAN_NB + b] = run;
}

__global__ void k_scan2(int* part, int* rowptr){
  int g = blockIdx.x;
  if(threadIdx.x) return;
  int* p = part + g*SCAN_NB;
  int run=0;
  for(int i=0;i<SCAN_NB;i++){ int t=p[i]; p[i]=run; run+=t; }
  rowptr[(size_t)g*NP1 + N_] = run;
}

__global__ __launch_bounds__(256) void k_scan3(int* rowptr, const int* __restrict__ part, int* cur){
  int g=blockIdx.y, b=blockIdx.x, t=threadIdx.x;
  int base = part[g*SCAN_NB+b];
  int i0 = b*SCAN_B + t*4;
  int* rp = rowptr + (size_t)g*NP1;
  int* cu = cur + (size_t)g*N_;
  #pragma unroll
  for(int j=0;j<4;j++){ int i=i0+j; if(i<N_){ int v=rp[i]+base; rp[i]=v; cu[i]=v; } }
}

__global__ void k_fill(const int* __restrict__ src,const int* __restrict__ dst,int ne,
                       int* cur,int* eidA,int* srcA){
  int e = blockIdx.x*blockDim.x + threadIdx.x;
  if(e>=ne) return;
  int d = dst[e];
  int pos = atomicAdd(&cur[d],1);
  eidA[pos]=e; srcA[pos]=src[e];
}

// per-graph raw edge_attr column sums + global column sum (256 threads = 4 row-groups x 64 f)
__global__ __launch_bounds__(256) void k_graph_easum(const int* dflag, const void* ea,
                              const int* es, const int* ee, float* gsum, float* gl){
  int g=blockIdx.x, t=threadIdx.x;
  int f=t&63, q=t>>6;
  int s=es[g], e=ee[g];
  float acc=0.f;
  if(*dflag){ for(int i=s+q;i<e;i+=4) acc += ((const float*)ea)[(size_t)i*64+f]; }
  else      { for(int i=s+q;i<e;i+=4) acc += b2f(((const bf16*)ea)[(size_t)i*64+f]); }
  __shared__ float red[256];
  red[t]=acc; __syncthreads();
  if(t<128) red[t]+=red[t+128];
  __syncthreads();
  if(t<64){
    float v = red[t]+red[t+64];
    gsum[(size_t)g*64+t]=v;
    atomicAdd(&gl[t], v);
  }
}

__global__ void k_loopae(const float* sumea, const float* v_edge, float* loopae, float invE){
  int h = threadIdx.x; if(h>=2) return;
  float acc=0.f;
  for(int f=0; f<64; f++) acc += sumea[f]*v_edge[h*64+f];
  loopae[h] = acc*invE;
}

template<typename TE>
static __device__ void eags_body(int idx,const float* gsum,const int* es,const int* ee,
                                 const void* W_lu,const void* b_lu,float* ea_gs){
  int g=idx>>6, f=idx&63;
  float acc=0.f;
  for(int k=0;k<64;k++) acc += gsum[g*64+k]*ldv<TE>(W_lu,f*64+k);
  float cnt=(float)(ee[g]-es[g]);
  ea_gs[idx]=acc + cnt*ldv<TE>(b_lu,f);
}
__global__ void k_ea_gs(const int* dflag,const float* gsum,const int* es,const int* ee,
                        const void* W_lu,const void* b_lu,float* ea_gs){
  int idx = blockIdx.x*blockDim.x + threadIdx.x;
  if(idx>=G_*64) return;
  if(*dflag) eags_body<float>(idx,gsum,es,ee,W_lu,b_lu,ea_gs);
  else       eags_body<bf16 >(idx,gsum,es,ee,W_lu,b_lu,ea_gs);
}

template<typename TE>
static __device__ void hge_body(int idx,const float* ea_gs,const void* W_re,const void* b_re,float* hge){
  int g=idx>>7, o=idx&127;
  float acc=0.f;
  for(int f=0;f<64;f++) acc += ea_gs[g*64+f]*ldv<TE>(W_re,(size_t)o*64+f);
  acc += ldv<TE>(b_re,o);
  hge[idx]=acc>0.f?acc:0.f;
}
__global__ void k_hge(const int* dflag,const float* ea_gs,const void* W_re,const void* b_re,float* hge){
  int idx = blockIdx.x*blockDim.x + threadIdx.x;
  if(idx>=G_*128) return;
  if(*dflag) hge_body<float>(idx,ea_gs,W_re,b_re,hge);
  else       hge_body<bf16 >(idx,ea_gs,W_re,b_re,hge);
}

// ---------------- tiled dense: out[M,64] = act(A[M,K] @ W[64,K]^T + bias) ----------------
// 64 rows x 64 cols per block, K-chunked by 64. Bank-remapped W (om) + stride-68 LDS.
template<int K>
__global__ __launch_bounds__(256) void k_dense_t(const int* dflag,int aExt,int outExt,
    const void* A,const void* W,const void* bias,void* out,size_t outOff,int M,int act){
  __shared__ float sA[64*68];
  __shared__ float sW[64*68];
  __shared__ float sB[64];
  const int t=threadIdx.x;
  const int n0=blockIdx.x*64;
  const int f32=*dflag;
  const bool aF32 = f32 && aExt;
  const bool oF32 = f32 && outExt;
  if(t<64) sB[t] = bias ? (f32? ((const float*)bias)[t] : b2f(((const bf16*)bias)[t])) : 0.f;
  float s[4][4];
  #pragma unroll
  for(int i=0;i<4;i++)
    #pragma unroll
    for(int j=0;j<4;j++) s[i][j]=0.f;
  const int cg=t&15, rg=t>>4;
  for(int kc=0;kc<K;kc+=64){
    // stage W chunk with bank remap
    for(int i=t;i<4096;i+=256){
      int o=i>>6, k=i&63;
      float v = f32 ? ((const float*)W)[(size_t)o*K+kc+k]
                    : b2f(((const bf16*)W)[(size_t)o*K+kc+k]);
      int om=(o>>2)|((o&3)<<4);
      sW[om*68+k]=v;
    }
    // stage A chunk
    if(aF32){
      for(int i=t;i<1024;i+=256){
        int m=i>>4, k4=(i&15)*4; int n=n0+m;
        float4 v = make_float4(0.f,0.f,0.f,0.f);
        if(n<M) v = *(const float4*)((const float*)A + (size_t)n*K + kc + k4);
        *(float4*)&sA[m*68+k4] = v;
      }
    } else {
      for(int i=t;i<512;i+=256){
        int m=i>>3, k8=(i&7)*8; int n=n0+m;
        float4 v0=make_float4(0.f,0.f,0.f,0.f), v1=v0;
        if(n<M){
          uint4 u = *(const uint4*)((const bf16*)A + (size_t)n*K + kc + k8);
          v0.x=bfu(u.x&0xffffu); v0.y=bfu(u.x>>16); v0.z=bfu(u.y&0xffffu); v0.w=bfu(u.y>>16);
          v1.x=bfu(u.z&0xffffu); v1.y=bfu(u.z>>16); v1.z=bfu(u.w&0xffffu); v1.w=bfu(u.w>>16);
        }
        *(float4*)&sA[m*68+k8]   = v0;
        *(float4*)&sA[m*68+k8+4] = v1;
      }
    }
    __syncthreads();
    #pragma unroll 4
    for(int k0=0;k0<64;k0+=4){
      float4 a[4], w[4];
      #pragma unroll
      for(int i=0;i<4;i++) a[i] = *(const float4*)&sA[(rg+16*i)*68 + k0];
      #pragma unroll
      for(int j=0;j<4;j++) w[j] = *(const float4*)&sW[(cg+16*j)*68 + k0];
      #pragma unroll
      for(int i=0;i<4;i++)
        #pragma unroll
        for(int j=0;j<4;j++)
          s[i][j] += a[i].x*w[j].x + a[i].y*w[j].y + a[i].z*w[j].z + a[i].w*w[j].w;
    }
    __syncthreads();
  }
  #pragma unroll
  for(int i=0;i<4;i++){
    int n = n0 + rg + 16*i;
    if(n>=M) continue;
    float vv[4];
    #pragma unroll
    for(int j=0;j<4;j++){
      float v = s[i][j] + sB[4*cg+j];
      if(act) v = v>0.f? v : 0.f;
      vv[j]=v;
    }
    if(oF32){
      float4 v4 = make_float4(vv[0],vv[1],vv[2],vv[3]);
      *(float4*)((float*)out + outOff + (size_t)n*64 + 4*cg) = v4;
    } else {
      union { bf16 h[4]; uint2 u; } pk;
      #pragma unroll
      for(int j=0;j<4;j++) pk.h[j]=f2b(vv[j]);
      *(uint2*)((bf16*)out + outOff + (size_t)n*64 + 4*cg) = pk.u;
    }
  }
}

// per-head transform of stage-A accumulator + bias + ELU (register-tiled, verified R1)
__global__ __launch_bounds__(256) void k_headelu(const int* dflag, const float* __restrict__ acc,
    const void* W, const void* bias, bf16* out, int nNodes){
  __shared__ float sA[64*68];
  __shared__ float sW[64*68];
  __shared__ float sB[64];
  const int t = threadIdx.x;
  const int half = blockIdx.y;
  const int n0 = blockIdx.x*64;
  const int f32 = *dflag;
  for(int i=t;i<4096;i+=256){
    int o=i>>6, k=i&63;
    float v = f32 ? ((const float*)W)[(size_t)(half*64+o)*64+k]
                  : b2f(((const bf16*)W)[(size_t)(half*64+o)*64+k]);
    int om = (o>>2) | ((o&3)<<4);
    sW[om*68+k] = v;
  }
  if(t<64) sB[t] = f32 ? ((const float*)bias)[half*64+t] : b2f(((const bf16*)bias)[half*64+t]);
  for(int i=t;i<1024;i+=256){
    int m=i>>4, k4=i&15;
    int n=n0+m;
    float4 v = make_float4(0.f,0.f,0.f,0.f);
    if(n<nNodes) v = *(const float4*)&acc[((size_t)(2*n+half))*64 + k4*4];
    *(float4*)&sA[m*68 + k4*4] = v;
  }
  __syncthreads();
  const int cg = t&15, rg = t>>4;
  float s[4][4];
  #pragma unroll
  for(int i=0;i<4;i++)
    #pragma unroll
    for(int j=0;j<4;j++) s[i][j]=0.f;
  #pragma unroll 4
  for(int k0=0;k0<64;k0+=4){
    float4 a[4], w[4];
    #pragma unroll
    for(int i=0;i<4;i++) a[i] = *(const float4*)&sA[(rg+16*i)*68 + k0];
    #pragma unroll
    for(int j=0;j<4;j++) w[j] = *(const float4*)&sW[(cg+16*j)*68 + k0];
    #pragma unroll
    for(int i=0;i<4;i++)
      #pragma unroll
      for(int j=0;j<4;j++)
        s[i][j] += a[i].x*w[j].x + a[i].y*w[j].y + a[i].z*w[j].z + a[i].w*w[j].w;
  }
  #pragma unroll
  for(int i=0;i<4;i++){
    int n = n0 + rg + 16*i;
    if(n>=nNodes) continue;
    union { bf16 h[4]; uint2 u; } pk;
    #pragma unroll
    for(int j=0;j<4;j++){
      float v = s[i][j] + sB[4*cg+j];
      v = v>0.f ? v : expf(v)-1.f;
      pk.h[j] = f2b(v);
    }
    *(uint2*)&out[((size_t)(2*n+half))*64 + 4*cg] = pk.u;
  }
}

// per-node alphas
__global__ void k_node_alpha(const int* dflag,int aExt,int K,const void* X,
                             const float* __restrict__ cva,const float* __restrict__ cvb,
                             float* oa,float* ob,int n){
  int i = blockIdx.x*blockDim.x + threadIdx.x;
  if(i>=n) return;
  float a0=0,a1=0,b0=0,b1=0;
  if(aExt && *dflag){
    const float* x=(const float*)X + (size_t)i*K;
    for(int k=0;k<K;k++){ float v=x[k]; a0+=v*cva[k]; a1+=v*cva[K+k]; b0+=v*cvb[k]; b1+=v*cvb[K+k]; }
  } else {
    const bf16* x=(const bf16*)X + (size_t)i*K;
    for(int k=0;k<K;k++){ float v=b2f(x[k]); a0+=v*cva[k]; a1+=v*cva[K+k]; b0+=v*cvb[k]; b1+=v*cvb[K+k]; }
  }
  oa[i*2]=a0; oa[i*2+1]=a1; ob[i*2]=b0; ob[i*2+1]=b1;
}

// edge alpha (no ssum — denominators computed inline by the gathers)
__global__ void k_edge_alpha(const int* dflag,
                             const float* __restrict__ asrc,const float* __restrict__ adst,
                             const int* __restrict__ srcI,const int* __restrict__ dstI,
                             int ne,int nloop,
                             const void* eattr,const float* __restrict__ vedge,
                             const float* __restrict__ loopae,
                             float* alpha){
  __shared__ float sv[128];
  int t = threadIdx.x;
  if(eattr){
    if(t<128) sv[t]=vedge[t];
    __syncthreads();
  }
  int e = blockIdx.x*blockDim.x + t;
  if(e>=ne+nloop) return;
  int s,d; float ae0=0.f, ae1=0.f;
  if(e<ne){
    s=srcI[e]; d=dstI[e];
    if(eattr){
      if(*dflag){
        const float4* row=(const float4*)((const float*)eattr + (size_t)e*64);
        #pragma unroll
        for(int k=0;k<16;k++){
          float4 v=row[k];
          ae0 += v.x*sv[4*k]   + v.y*sv[4*k+1]   + v.z*sv[4*k+2]   + v.w*sv[4*k+3];
          ae1 += v.x*sv[64+4*k]+ v.y*sv[64+4*k+1]+ v.z*sv[64+4*k+2]+ v.w*sv[64+4*k+3];
        }
      } else {
        const uint4* row=(const uint4*)((const bf16*)eattr + (size_t)e*64);
        #pragma unroll
        for(int k=0;k<8;k++){
          uint4 u=row[k];
          float f0=bfu(u.x&0xffffu), f1=bfu(u.x>>16), f2=bfu(u.y&0xffffu), f3=bfu(u.y>>16);
          float f4=bfu(u.z&0xffffu), f5=bfu(u.z>>16), f6=bfu(u.w&0xffffu), f7=bfu(u.w>>16);
          ae0 += f0*sv[8*k]+f1*sv[8*k+1]+f2*sv[8*k+2]+f3*sv[8*k+3]
               + f4*sv[8*k+4]+f5*sv[8*k+5]+f6*sv[8*k+6]+f7*sv[8*k+7];
          ae1 += f0*sv[64+8*k]+f1*sv[64+8*k+1]+f2*sv[64+8*k+2]+f3*sv[64+8*k+3]
               + f4*sv[64+8*k+4]+f5*sv[64+8*k+5]+f6*sv[64+8*k+6]+f7*sv[64+8*k+7];
        }
      }
    }
  } else {
    s=d=e-ne;
    if(eattr){ ae0=loopae[0]; ae1=loopae[1]; }
  }
  float l0 = asrc[s*2]  +adst[d*2]  +ae0; l0 = l0>0.f? l0 : 0.2f*l0;
  float l1 = asrc[s*2+1]+adst[d*2+1]+ae1; l1 = l1>0.f? l1 : 0.2f*l1;
  alpha[e*2]  = expf(fminf(l0,50.f));
  alpha[e*2+1]= expf(fminf(l1,50.f));
}

// stage-A gather: C[d][ch] = sum_in x[src][f]*alpha_h / sum_in alpha_h  (incl self-loop)
__global__ __launch_bounds__(256) void k_gatherA(const int* dflag,const void* X,
    const float* __restrict__ alpha,const int* __restrict__ rowptr,
    const int* __restrict__ eidA,const int* __restrict__ srcA,
    int ne,float* out){
  int t=threadIdx.x;
  int d=blockIdx.x*2 + (t>>7);
  if(d>=N_) return;
  int ch=t&127, h=ch>>6, f=ch&63;
  int f32=*dflag;
  int j0=rowptr[d], j1=rowptr[d+1];
  float acc=0.f, ss=0.f;
  for(int j=j0;j<j1;j++){
    int eid=eidA[j], s=srcA[j];
    float a=alpha[eid*2+h];
    float xv = f32? ((const float*)X)[(size_t)s*64+f] : b2f(((const bf16*)X)[(size_t)s*64+f]);
    acc+=xv*a; ss+=a;
  }
  {
    float a=alpha[(size_t)(ne+d)*2+h];
    float xv = f32? ((const float*)X)[(size_t)d*64+f] : b2f(((const bf16*)X)[(size_t)d*64+f]);
    acc+=xv*a; ss+=a;
  }
  out[(size_t)d*128+ch]=acc/(ss+1e-16f);
}

// stage-2 gather (+bias fusion): rep[d][colOff+ch] = sum_in msg[src][ch]*alpha_h / ssum + bias[ch]
__global__ __launch_bounds__(256) void k_gather64(const int* dflag,const bf16* __restrict__ msg,
    const float* __restrict__ alpha,const int* __restrict__ rowptr,
    const int* __restrict__ eidA,const int* __restrict__ srcA,
    int ne,float* rep,int colOff,const void* bias){
  int t=threadIdx.x;
  int d=blockIdx.x*4 + (t>>6);
  if(d>=N_) return;
  int ch=t&63, h=ch>>5;
  int j0=rowptr[d], j1=rowptr[d+1];
  float acc=0.f, ss=0.f;
  for(int j=j0;j<j1;j++){
    int eid=eidA[j], s=srcA[j];
    float a=alpha[eid*2+h];
    acc += b2f(msg[(size_t)s*64+ch])*a; ss+=a;
  }
  {
    float a=alpha[(size_t)(ne+d)*2+h];
    acc += b2f(msg[(size_t)d*64+ch])*a; ss+=a;
  }
  float b = (*dflag)? ((const float*)bias)[ch] : b2f(((const bf16*)bias)[ch]);
  rep[(size_t)d*128+colOff+ch]=acc/(ss+1e-16f)+b;
}

template<typename TE>
static __device__ void zscore_body(int i,const float* rep,const void* W_rel,const void* b_rel,
                                   const void* W_root,float* z,float* score){
  const float* r = rep + (size_t)i*128;
  float zz=0.f, rr=0.f;
  for(int f=0;f<128;f++){ float v=r[f]; zz+=v*ldv<TE>(W_rel,f); rr+=v*ldv<TE>(W_root,f); }
  z[i]=zz; score[i]=rr+ldv<TE>(b_rel,0);
}
__global__ void k_zscore(const int* dflag,const float* __restrict__ rep,
                         const void* W_rel,const void* b_rel,const void* W_root,
                         float* z,float* score,int n){
  int i = blockIdx.x*blockDim.x + threadIdx.x;
  if(i>=n) return;
  if(*dflag) zscore_body<float>(i,rep,W_rel,b_rel,W_root,z,score);
  else       zscore_body<bf16 >(i,rep,W_rel,b_rel,W_root,z,score);
}

__global__ void k_score_scatter(const float* __restrict__ z,const int* __restrict__ srcI,
                                const int* __restrict__ dstI,float* score,int ne){
  int e = blockIdx.x*blockDim.x + threadIdx.x;
  if(e>=ne) return;
  atomicAdd(&score[dstI[e]], z[srcI[e]]);
}

// SAG readout with per-graph max-subtracted softmax
__global__ void k_readout(const int* dflag,const float* __restrict__ rep,const float* __restrict__ score,
                          const int* ns,const int* ne,const float* __restrict__ hge,
                          void* out,size_t outOff){
  int g = blockIdx.x; int tid = threadIdx.x;
  int s = ns[g], e = ne[g];
  __shared__ float red[128];
  float m=-1e30f;
  for(int n=s+tid;n<e;n+=128) m=fmaxf(m,score[n]);
  red[tid]=m; __syncthreads();
  for(int w=64;w>0;w>>=1){ if(tid<w) red[tid]=fmaxf(red[tid],red[tid+w]); __syncthreads(); }
  float M=red[0]; __syncthreads();
  float loc=0.f;
  for(int n=s+tid;n<e;n+=128) loc += expf(score[n]-M);
  red[tid]=loc; __syncthreads();
  for(int w=64;w>0;w>>=1){ if(tid<w) red[tid]+=red[tid+w]; __syncthreads(); }
  float inv = 1.f/(red[0]+1e-16f);
  float acc=0.f;
  for(int n=s;n<e;n++) acc += rep[(size_t)n*128+tid]*expf(score[n]-M);
  float v = acc*inv + hge[g*128+tid];
  if(*dflag) ((float*)out)[outOff+(size_t)g*128+tid]=v;
  else       ((bf16 *)out)[outOff+(size_t)g*128+tid]=f2b(v);
}

// graph LayerNorm (mode='graph') + relu
__global__ void k_ln(const int* dflag,const float* __restrict__ rep,const int* ns,const int* ne,
                     const void* lnw,const void* lnb,void* out,size_t outOff){
  int g = blockIdx.x; int tid = threadIdx.x;
  int s = ns[g], e = ne[g];
  __shared__ float r1[128];
  float sm=0.f, sq=0.f;
  for(int n=s;n<e;n++){ float v=rep[(size_t)n*128+tid]; sm+=v; sq+=v*v; }
  r1[tid]=sm; __syncthreads();
  for(int w=64;w>0;w>>=1){ if(tid<w) r1[tid]+=r1[tid+w]; __syncthreads(); }
  float S = r1[0]; __syncthreads();
  r1[tid]=sq; __syncthreads();
  for(int w=64;w>0;w>>=1){ if(tid<w) r1[tid]+=r1[tid+w]; __syncthreads(); }
  float SQ = r1[0];
  float cnt=(float)(e-s);
  float norm = (cnt>1.f? cnt:1.f)*128.f;
  float mean = S/norm;
  float var = SQ/norm - mean*mean;
  var = var>0.f? var:0.f;
  float inv = rsqrtf(var+1e-5f);
  int f32 = *dflag;
  float wf,bb;
  if(f32){ wf=((const float*)lnw)[tid]; bb=((const float*)lnb)[tid]; }
  else   { wf=b2f(((const bf16*)lnw)[tid]); bb=b2f(((const bf16*)lnb)[tid]); }
  for(int n=s;n<e;n++){
    float v=(rep[(size_t)n*128+tid]-mean)*inv*wf+bb;
    v = v>0.f? v:0.f;
    if(f32) ((float*)out)[outOff+(size_t)n*128+tid]=v;
    else    ((bf16 *)out)[outOff+(size_t)n*128+tid]=f2b(v);
  }
}

extern "C" void kernel_launch(void* const* d_in, const int* in_sizes, int n_in,
                              void* d_out, int out_size, void* d_ws, size_t ws_size,
                              hipStream_t stream) {
  const void* x_h      = d_in[0];
  const void* x_t      = d_in[1];
  const void* eat_h    = d_in[2];
  const void* eat_t    = d_in[3];
  const int*  ei_h     = (const int*)d_in[4];
  const int*  ei_t     = (const int*)d_in[5];
  const int*  bei      = (const int*)d_in[6];
  const int*  batch_h  = (const int*)d_in[7];
  const int*  batch_t  = (const int*)d_in[8];
  const int*  ebat_h   = (const int*)d_in[9];
  const int*  ebat_t   = (const int*)d_in[10];
  const void* W_fc     = d_in[11];
  const void* a_s_fc   = d_in[12];
  const void* a_d_fc   = d_in[13];
  const void* W_e      = d_in[14];
  const void* a_e      = d_in[15];
  const void* b_fc     = d_in[16];
  const void* W_lu     = d_in[17];
  const void* b_lu     = d_in[18];
  const void* W_i      = d_in[19];
  const void* a_s_i    = d_in[20];
  const void* a_d_i    = d_in[21];
  const void* b_intra  = d_in[22];
  const void* W_bs     = d_in[23];
  const void* W_bd     = d_in[24];
  const void* a_s_b    = d_in[25];
  const void* a_d_b    = d_in[26];
  const void* b_inter  = d_in[27];
  const void* W_rel    = d_in[28];
  const void* b_rel    = d_in[29];
  const void* W_root   = d_in[30];
  const void* ln_w     = d_in[31];
  const void* ln_b     = d_in[32];
  const void* W_re     = d_in[33];
  const void* b_re     = d_in[34];

  // output element offsets (elements, in output dtype)
  const size_t o_hx  = 0;
  const size_t o_eah = (size_t)N_*128;
  const size_t o_tx  = o_eah + (size_t)E_*64;
  const size_t o_eat = o_tx  + (size_t)N_*128;
  const size_t o_hg  = o_eat + (size_t)E_*64;
  const size_t o_tg  = o_hg  + (size_t)G_*128;

  // ---- d_out as mid-pipeline scratch (bf16-indexed; all dead before final writes) ----
  bf16* eh   = (bf16*)d_out + o_hx;
  bf16* et   = (bf16*)d_out + o_tx;
  bf16* msgI_h = (bf16*)d_out + o_eah;
  bf16* msgI_t = msgI_h + (size_t)N_*64;
  bf16* msgB_h = msgI_h + (size_t)2*N_*64;
  bf16* msgB_t = msgI_h + (size_t)3*N_*64;
  float* areg  = (float*)((bf16*)d_out + o_eat);
  float* alpha1_h  = areg;
  float* alpha1_t  = areg + (size_t)(E_+N_)*2;
  float* alpha2_ih = areg + (size_t)2*(E_+N_)*2;
  float* alpha2_it = areg + (size_t)3*(E_+N_)*2;
  float* alpha2_bt = alpha1_h;   // alias: alpha1 dead before stage-2 bipartite
  float* alpha2_bh = alpha1_t;
  // CSR arrays after the 4 alpha arrays (16MB); dead before final dense overwrites
  int* csr_base = (int*)(areg + (size_t)4*(E_+N_)*2);
  int* eid0 = csr_base;                 int* eid1 = csr_base + (size_t)E_;
  int* eid2 = csr_base + (size_t)2*E_;  int* eid3 = csr_base + (size_t)3*E_;
  int* src0 = csr_base + (size_t)4*E_;  int* src1 = csr_base + (size_t)5*E_;
  int* src2 = csr_base + (size_t)6*E_;  int* src3 = csr_base + (size_t)7*E_;

  // ---------------- workspace arena ----------------
  char* p = (char*)d_ws;
  size_t off = 0;
  auto alloc = [&](size_t bytes)->char*{
    char* r = p + off; off += (bytes + 255) & ~(size_t)255; return r;
  };
  int* dflag=(int*)alloc(256);
  int* es_h = (int*)alloc(G_*4); int* ee_h = (int*)alloc(G_*4);
  int* es_t = (int*)alloc(G_*4); int* ee_t = (int*)alloc(G_*4);
  int* ns_h = (int*)alloc(G_*4); int* ne_h = (int*)alloc(G_*4);
  int* ns_t = (int*)alloc(G_*4); int* ne_t = (int*)alloc(G_*4);
  float* sumea_h = (float*)alloc(64*4);
  float* sumea_t = (float*)alloc(64*4);
  float* c_fc_s=(float*)alloc(128*4); float* c_fc_d=(float*)alloc(128*4);
  float* v_edge=(float*)alloc(128*4);
  float* c_i_s=(float*)alloc(256*4);  float* c_i_d=(float*)alloc(256*4);
  float* c_b_s=(float*)alloc(256*4);  float* c_b_d=(float*)alloc(256*4);
  float* lae_h=(float*)alloc(2*4);    float* lae_t=(float*)alloc(2*4);
  int* cnt    = (int*)alloc((size_t)4*N_*4);
  int* cur    = (int*)alloc((size_t)4*N_*4);
  int* rowptr = (int*)alloc((size_t)4*NP1*4);
  int* part   = (int*)alloc((size_t)4*SCAN_NB*4);
  float* a1s_h=(float*)alloc((size_t)N_*2*4); float* a1d_h=(float*)alloc((size_t)N_*2*4);
  float* a1s_t=(float*)alloc((size_t)N_*2*4); float* a1d_t=(float*)alloc((size_t)N_*2*4);
  float* ais_h=(float*)alloc((size_t)N_*2*4); float* aid_h=(float*)alloc((size_t)N_*2*4);
  float* ais_t=(float*)alloc((size_t)N_*2*4); float* aid_t=(float*)alloc((size_t)N_*2*4);
  float* abs_h=(float*)alloc((size_t)N_*2*4); float* abd_h=(float*)alloc((size_t)N_*2*4);
  float* abs_t=(float*)alloc((size_t)N_*2*4); float* abd_t=(float*)alloc((size_t)N_*2*4);
  float* z_h=(float*)alloc((size_t)N_*4); float* z_t=(float*)alloc((size_t)N_*4);
  float* sc_h=(float*)alloc((size_t)N_*4); float* sc_t=(float*)alloc((size_t)N_*4);
  float* gsum_h=(float*)alloc((size_t)G_*64*4); float* gsum_t=(float*)alloc((size_t)G_*64*4);
  float* eags_h=(float*)alloc((size_t)G_*64*4); float* eags_t=(float*)alloc((size_t)G_*64*4);
  float* hge_h =(float*)alloc((size_t)G_*128*4); float* hge_t =(float*)alloc((size_t)G_*128*4);
  float* C = (float*)alloc((size_t)N_*128*4);   // stage-A acc (h,t) then t_rep
  float* D = (float*)alloc((size_t)N_*128*4);   // h_rep
  float* t_rep = C;
  float* h_rep = D;

  int* rp0 = rowptr;                  int* rp1 = rowptr + (size_t)NP1;
  int* rp2 = rowptr + (size_t)2*NP1;  int* rp3 = rowptr + (size_t)3*NP1;

  auto cdiv=[](long a, long b){ return (int)((a+b-1)/b); };

  // ---------------- phase 0: probe, zero, setup ----------------
  k_detect<<<1,256,0,stream>>>(x_h, dflag);
  hipMemsetAsync(es_h, 0, (size_t)G_*4*8, stream);
  hipMemsetAsync(sumea_h, 0, 512, stream);
  hipMemsetAsync(cnt, 0, (size_t)4*N_*4, stream);

  k_combine<<<6,256,0,stream>>>(dflag, W_fc,a_s_fc,a_d_fc, W_e,a_e, W_i,a_s_i,a_d_i,
                                W_bs,W_bd,a_s_b,a_d_b,
                                c_fc_s,c_fc_d,v_edge,c_i_s,c_i_d,c_b_s,c_b_d);
  k_ranges<<<cdiv(E_,256),256,0,stream>>>(ebat_h, E_, es_h, ee_h);
  k_ranges<<<cdiv(E_,256),256,0,stream>>>(ebat_t, E_, es_t, ee_t);
  k_ranges<<<cdiv(N_,256),256,0,stream>>>(batch_h, N_, ns_h, ne_h);
  k_ranges<<<cdiv(N_,256),256,0,stream>>>(batch_t, N_, ns_t, ne_t);

  // ---------------- CSR build (4 incoming-edge CSRs) ----------------
  k_hist<<<cdiv(E_,256),256,0,stream>>>(ei_h+E_, E_, cnt);
  k_hist<<<cdiv(E_,256),256,0,stream>>>(ei_t+E_, E_, cnt + (size_t)N_);
  k_hist<<<cdiv(EBI,256),256,0,stream>>>(bei+EBI, EBI, cnt + (size_t)2*N_);   // fwd: dst=t
  k_hist<<<cdiv(EBI,256),256,0,stream>>>(bei,     EBI, cnt + (size_t)3*N_);   // rev: dst=h
  k_scan1<<<dim3(SCAN_NB,4),256,0,stream>>>(cnt, rowptr, part);
  k_scan2<<<4,32,0,stream>>>(part, rowptr);
  k_scan3<<<dim3(SCAN_NB,4),256,0,stream>>>(rowptr, part, cur);
  k_fill<<<cdiv(E_,256),256,0,stream>>>(ei_h,    ei_h+E_, E_,  cur,               eid0, src0);
  k_fill<<<cdiv(E_,256),256,0,stream>>>(ei_t,    ei_t+E_, E_,  cur+(size_t)N_,    eid1, src1);
  k_fill<<<cdiv(EBI,256),256,0,stream>>>(bei,    bei+EBI, EBI, cur+(size_t)2*N_,  eid2, src2);
  k_fill<<<cdiv(EBI,256),256,0,stream>>>(bei+EBI,bei,     EBI, cur+(size_t)3*N_,  eid3, src3);

  // ---------------- edge-graph pooling path ----------------
  k_graph_easum<<<G_,256,0,stream>>>(dflag, eat_h, es_h, ee_h, gsum_h, sumea_h);
  k_graph_easum<<<G_,256,0,stream>>>(dflag, eat_t, es_t, ee_t, gsum_t, sumea_t);
  k_loopae<<<1,64,0,stream>>>(sumea_h, v_edge, lae_h, 1.f/(float)E_);
  k_loopae<<<1,64,0,stream>>>(sumea_t, v_edge, lae_t, 1.f/(float)E_);
  k_ea_gs<<<cdiv(G_*64,256),256,0,stream>>>(dflag, gsum_h, es_h, ee_h, W_lu, b_lu, eags_h);
  k_ea_gs<<<cdiv(G_*64,256),256,0,stream>>>(dflag, gsum_t, es_t, ee_t, W_lu, b_lu, eags_t);
  k_hge<<<cdiv(G_*128,256),256,0,stream>>>(dflag, eags_h, W_re, b_re, hge_h);
  k_hge<<<cdiv(G_*128,256),256,0,stream>>>(dflag, eags_t, W_re, b_re, hge_t);

  // ---------------- stage A: feature GATConv ----------------
  k_node_alpha<<<cdiv(N_,256),256,0,stream>>>(dflag,1,64, x_h, c_fc_s, c_fc_d, a1s_h, a1d_h, N_);
  k_node_alpha<<<cdiv(N_,256),256,0,stream>>>(dflag,1,64, x_t, c_fc_s, c_fc_d, a1s_t, a1d_t, N_);
  k_edge_alpha<<<cdiv(E_+N_,256),256,0,stream>>>(dflag, a1s_h, a1d_h, ei_h, ei_h+E_, E_, N_,
                                                 eat_h, v_edge, lae_h, alpha1_h);
  k_edge_alpha<<<cdiv(E_+N_,256),256,0,stream>>>(dflag, a1s_t, a1d_t, ei_t, ei_t+E_, E_, N_,
                                                 eat_t, v_edge, lae_t, alpha1_t);
  dim3 ghe((unsigned)cdiv(N_,64), 2);
  k_gatherA<<<cdiv(N_,2),256,0,stream>>>(dflag, x_h, alpha1_h, rp0, eid0, src0, E_, C);
  k_headelu<<<ghe,256,0,stream>>>(dflag, C, W_fc, b_fc, eh, N_);
  k_gatherA<<<cdiv(N_,2),256,0,stream>>>(dflag, x_t, alpha1_t, rp1, eid1, src1, E_, C);
  k_headelu<<<ghe,256,0,stream>>>(dflag, C, W_fc, b_fc, et, N_);

  // ---------------- stage 2: message transforms + per-node alphas ----------------
  k_dense_t<128><<<cdiv(N_,64),256,0,stream>>>(dflag,0,0, eh, W_i,  nullptr, msgI_h, 0, N_, 0);
  k_dense_t<128><<<cdiv(N_,64),256,0,stream>>>(dflag,0,0, et, W_i,  nullptr, msgI_t, 0, N_, 0);
  k_dense_t<128><<<cdiv(N_,64),256,0,stream>>>(dflag,0,0, eh, W_bs, nullptr, msgB_h, 0, N_, 0);
  k_dense_t<128><<<cdiv(N_,64),256,0,stream>>>(dflag,0,0, et, W_bs, nullptr, msgB_t, 0, N_, 0);
  k_node_alpha<<<cdiv(N_,256),256,0,stream>>>(dflag,0,128, eh, c_i_s, c_i_d, ais_h, aid_h, N_);
  k_node_alpha<<<cdiv(N_,256),256,0,stream>>>(dflag,0,128, et, c_i_s, c_i_d, ais_t, aid_t, N_);
  k_node_alpha<<<cdiv(N_,256),256,0,stream>>>(dflag,0,128, eh, c_b_s, c_b_d, abs_h, abd_h, N_);
  k_node_alpha<<<cdiv(N_,256),256,0,stream>>>(dflag,0,128, et, c_b_s, c_b_d, abs_t, abd_t, N_);

  // ---------------- stage 2: GAT aggregation (gathers, bias fused) ----------------
  k_edge_alpha<<<cdiv(E_+N_,256),256,0,stream>>>(dflag, ais_h, aid_h, ei_h, ei_h+E_, E_, N_,
                                                 nullptr,nullptr,nullptr, alpha2_ih);
  k_edge_alpha<<<cdiv(E_+N_,256),256,0,stream>>>(dflag, ais_t, aid_t, ei_t, ei_t+E_, E_, N_,
                                                 nullptr,nullptr,nullptr, alpha2_it);
  k_edge_alpha<<<cdiv(EBI+N_,256),256,0,stream>>>(dflag, abs_h, abd_t, bei, bei+EBI, EBI, N_,
                                                 nullptr,nullptr,nullptr, alpha2_bt);
  k_edge_alpha<<<cdiv(EBI+N_,256),256,0,stream>>>(dflag, abs_t, abd_h, bei+EBI, bei, EBI, N_,
                                                 nullptr,nullptr,nullptr, alpha2_bh);
  k_gather64<<<cdiv(N_,4),256,0,stream>>>(dflag, msgI_h, alpha2_ih, rp0, eid0, src0, E_,  h_rep, 0,  b_intra);
  k_gather64<<<cdiv(N_,4),256,0,stream>>>(dflag, msgI_t, alpha2_it, rp1, eid1, src1, E_,  t_rep, 0,  b_intra);
  k_gather64<<<cdiv(N_,4),256,0,stream>>>(dflag, msgB_h, alpha2_bt, rp2, eid2, src2, EBI, t_rep, 64, b_inter);
  k_gather64<<<cdiv(N_,4),256,0,stream>>>(dflag, msgB_t, alpha2_bh, rp3, eid3, src3, EBI, h_rep, 64, b_inter);

  // ---------------- readout + LN ----------------
  k_zscore<<<cdiv(N_,256),256,0,stream>>>(dflag, h_rep, W_rel, b_rel, W_root, z_h, sc_h, N_);
  k_zscore<<<cdiv(N_,256),256,0,stream>>>(dflag, t_rep, W_rel, b_rel, W_root, z_t, sc_t, N_);
  k_score_scatter<<<cdiv(E_,256),256,0,stream>>>(z_h, ei_h, ei_h+E_, sc_h, E_);
  k_score_scatter<<<cdiv(E_,256),256,0,stream>>>(z_t, ei_t, ei_t+E_, sc_t, E_);
  k_readout<<<G_,128,0,stream>>>(dflag, h_rep, sc_h, ns_h, ne_h, hge_h, d_out, o_hg);
  k_readout<<<G_,128,0,stream>>>(dflag, t_rep, sc_t, ns_t, ne_t, hge_t, d_out, o_tg);
  k_ln<<<G_,128,0,stream>>>(dflag, h_rep, ns_h, ne_h, ln_w, ln_b, d_out, o_hx);
  k_ln<<<G_,128,0,stream>>>(dflag, t_rep, ns_t, ne_t, ln_w, ln_b, d_out, o_tx);

  // ---------------- final: relu(ea) outputs ----------------
  k_dense_t<64><<<cdiv(E_,64),256,0,stream>>>(dflag,1,1, eat_h, W_lu, b_lu, d_out, o_eah, E_, 1);
  k_dense_t<64><<<cdiv(E_,64),256,0,stream>>>(dflag,1,1, eat_t, W_lu, b_lu, d_out, o_eat, E_, 1);

  (void)in_sizes; (void)n_in; (void)out_size; (void)ws_size;
}

// Round 3
// 1974.860 us; speedup vs baseline: 1.9593x; 1.1635x over previous
//
#include <hip/hip_runtime.h>
#include <hip/hip_bf16.h>

typedef __hip_bfloat16 bf16;

#define N_  100000
#define E_  400000
#define EBI 400000
#define G_  2048
#define NP1 (N_+1)
#define SCAN_B 1024
#define SCAN_NB ((N_+SCAN_B-1)/SCAN_B)

static __device__ __forceinline__ float b2f(bf16 v){ return __bfloat162float(v); }
static __device__ __forceinline__ bf16  f2b(float v){ return __float2bfloat16(v); }
static __device__ __forceinline__ float bfu(unsigned int u){
  union{unsigned int i; float f;} x; x.i = u<<16; return x.f;
}

template<typename T> static __device__ __forceinline__ float ldv(const void* p, size_t i){
  return (float)((const T*)p)[i];
}

// ---------------- dtype probe ----------------
__global__ void k_detect(const void* x, int* flag){
  __shared__ int cnt;
  if(threadIdx.x==0) cnt=0;
  __syncthreads();
  float v = fabsf(b2f(((const bf16*)x)[(size_t)threadIdx.x*2]));
  if(v>1e-3f && v<16.f) atomicAdd(&cnt,1);
  __syncthreads();
  if(threadIdx.x==0) *flag = (cnt<128) ? 1 : 0;   // 1 = external tensors are f32
}

// ---------------- combined attention vectors ----------------
template<typename TE>
static __device__ void combine_body(int idx,
    const void* W_fc,const void* a_s_fc,const void* a_d_fc,
    const void* W_e,const void* a_e,
    const void* W_i,const void* a_s_i,const void* a_d_i,
    const void* W_bs,const void* W_bd,const void* a_s_b,const void* a_d_b,
    float* c_fc_s,float* c_fc_d,float* v_edge,
    float* c_i_s,float* c_i_d,float* c_b_s,float* c_b_d){
  if(idx<384){
    int which=idx>>7; int r=idx&127; int h=r>>6, f=r&63;
    const void* W   = (which==2)? W_e : W_fc;
    const void* att = (which==0)? a_s_fc : (which==1)? a_d_fc : a_e;
    float acc=0.f;
    for(int c=0;c<64;c++) acc += ldv<TE>(W,(size_t)(h*64+c)*64+f)*ldv<TE>(att,h*64+c);
    ((which==0)? c_fc_s : (which==1)? c_fc_d : v_edge)[r]=acc;
  } else if(idx<1408){
    int t=idx-384; int which=t>>8; int r=t&255; int h=r>>7, f=r&127;
    const void* W   = (which<=1)? W_i : (which==2)? W_bs : W_bd;
    const void* att = (which==0)? a_s_i : (which==1)? a_d_i : (which==2)? a_s_b : a_d_b;
    float acc=0.f;
    for(int c=0;c<32;c++) acc += ldv<TE>(W,(size_t)(h*32+c)*128+f)*ldv<TE>(att,h*32+c);
    ((which==0)? c_i_s:(which==1)? c_i_d:(which==2)? c_b_s:c_b_d)[r]=acc;
  }
}
__global__ void k_combine(const int* dflag,
    const void* W_fc,const void* a_s_fc,const void* a_d_fc,
    const void* W_e,const void* a_e,
    const void* W_i,const void* a_s_i,const void* a_d_i,
    const void* W_bs,const void* W_bd,const void* a_s_b,const void* a_d_b,
    float* c_fc_s,float* c_fc_d,float* v_edge,
    float* c_i_s,float* c_i_d,float* c_b_s,float* c_b_d){
  int idx = blockIdx.x*blockDim.x + threadIdx.x;
  if(*dflag) combine_body<float>(idx,W_fc,a_s_fc,a_d_fc,W_e,a_e,W_i,a_s_i,a_d_i,W_bs,W_bd,a_s_b,a_d_b,
                                 c_fc_s,c_fc_d,v_edge,c_i_s,c_i_d,c_b_s,c_b_d);
  else       combine_body<bf16 >(idx,W_fc,a_s_fc,a_d_fc,W_e,a_e,W_i,a_s_i,a_d_i,W_bs,W_bd,a_s_b,a_d_b,
                                 c_fc_s,c_fc_d,v_edge,c_i_s,c_i_d,c_b_s,c_b_d);
}

// ---------------- sorted-segment ranges (4 jobs via grid.y) ----------------
__global__ void k_ranges4(const int* __restrict__ ebat_h,const int* __restrict__ ebat_t,
                          const int* __restrict__ batch_h,const int* __restrict__ batch_t,
                          int* es_h,int* ee_h,int* es_t,int* ee_t,
                          int* ns_h,int* ne_h,int* ns_t,int* ne_t){
  int i = blockIdx.x*blockDim.x + threadIdx.x;
  int y = blockIdx.y;
  const int* batch; int n; int *st,*en;
  if(y==0){ batch=ebat_h; n=E_; st=es_h; en=ee_h; }
  else if(y==1){ batch=ebat_t; n=E_; st=es_t; en=ee_t; }
  else if(y==2){ batch=batch_h; n=N_; st=ns_h; en=ne_h; }
  else { batch=batch_t; n=N_; st=ns_t; en=ne_t; }
  if(i>=n) return;
  int b = batch[i];
  if(i==0 || batch[i-1]!=b) st[b]=i;
  if(i==n-1 || batch[i+1]!=b) en[b]=i+1;
}

// ---------------- CSR build (4 CSRs via grid.y) ----------------
__global__ void k_hist4(const int* __restrict__ ei_h,const int* __restrict__ ei_t,
                        const int* __restrict__ bei,int* cnt){
  int e = blockIdx.x*blockDim.x + threadIdx.x;
  if(e>=E_) return;
  int y = blockIdx.y;
  const int* dst = (y==0)? ei_h+E_ : (y==1)? ei_t+E_ : (y==2)? bei+EBI : bei;
  atomicAdd(&cnt[(size_t)y*N_ + dst[e]],1);
}

__global__ __launch_bounds__(256) void k_scan1(const int* __restrict__ cnt, int* rowptr, int* part){
  int g = blockIdx.y, b = blockIdx.x, t = threadIdx.x;
  const int* c = cnt + (size_t)g*N_;
  int* rp = rowptr + (size_t)g*NP1;
  int i0 = b*SCAN_B + t*4;
  int v[4];
  #pragma unroll
  for(int j=0;j<4;j++){ int i=i0+j; v[j] = (i<N_)? c[i] : 0; }
  int T = v[0]+v[1]+v[2]+v[3];
  __shared__ int sh[256];
  sh[t]=T; __syncthreads();
  int run=T;
  for(int o=1;o<256;o<<=1){
    int add = (t>=o)? sh[t-o] : 0;
    __syncthreads();
    run += add; sh[t]=run;
    __syncthreads();
  }
  int p = run - T;   // exclusive prefix for this thread
  #pragma unroll
  for(int j=0;j<4;j++){ int i=i0+j; if(i<N_) rp[i]=p; p+=v[j]; }
  if(t==255) part[g*SCAN_NB + b] = run;
}

__global__ void k_scan2(int* part, int* rowptr){
  int g = blockIdx.x;
  if(threadIdx.x) return;
  int* p = part + g*SCAN_NB;
  int run=0;
  for(int i=0;i<SCAN_NB;i++){ int t=p[i]; p[i]=run; run+=t; }
  rowptr[(size_t)g*NP1 + N_] = run;
}

__global__ __launch_bounds__(256) void k_scan3(int* rowptr, const int* __restrict__ part, int* cur){
  int g=blockIdx.y, b=blockIdx.x, t=threadIdx.x;
  int base = part[g*SCAN_NB+b];
  int i0 = b*SCAN_B + t*4;
  int* rp = rowptr + (size_t)g*NP1;
  int* cu = cur + (size_t)g*N_;
  #pragma unroll
  for(int j=0;j<4;j++){ int i=i0+j; if(i<N_){ int v=rp[i]+base; rp[i]=v; cu[i]=v; } }
}

__global__ void k_fill4(const int* __restrict__ ei_h,const int* __restrict__ ei_t,
                        const int* __restrict__ bei,int* cur,int* eids,int* srcs){
  int e = blockIdx.x*blockDim.x + threadIdx.x;
  if(e>=E_) return;
  int y = blockIdx.y;
  const int *s,*d;
  if(y==0){ s=ei_h; d=ei_h+E_; }
  else if(y==1){ s=ei_t; d=ei_t+E_; }
  else if(y==2){ s=bei; d=bei+EBI; }
  else { s=bei+EBI; d=bei; }
  int dd = d[e];
  int pos = atomicAdd(&cur[(size_t)y*N_+dd],1);
  eids[(size_t)y*E_+pos]=e; srcs[(size_t)y*E_+pos]=s[e];
}

// per-graph raw edge_attr column sums + global column sum (both sides via grid.y)
__global__ __launch_bounds__(256) void k_graph_easum(const int* dflag,
                              const void* eat_h,const void* eat_t,
                              const int* es_h,const int* ee_h,const int* es_t,const int* ee_t,
                              float* gsum_h,float* gsum_t,float* gl_h,float* gl_t){
  int g=blockIdx.x, t=threadIdx.x, side=blockIdx.y;
  const void* ea = side? eat_t : eat_h;
  int s = side? es_t[g] : es_h[g];
  int e = side? ee_t[g] : ee_h[g];
  float* gsum = side? gsum_t : gsum_h;
  float* gl   = side? gl_t : gl_h;
  int f=t&63, q=t>>6;
  float acc=0.f;
  if(*dflag){ for(int i=s+q;i<e;i+=4) acc += ((const float*)ea)[(size_t)i*64+f]; }
  else      { for(int i=s+q;i<e;i+=4) acc += b2f(((const bf16*)ea)[(size_t)i*64+f]); }
  __shared__ float red[256];
  red[t]=acc; __syncthreads();
  if(t<128) red[t]+=red[t+128];
  __syncthreads();
  if(t<64){
    float v = red[t]+red[t+64];
    gsum[(size_t)g*64+t]=v;
    atomicAdd(&gl[t], v);
  }
}

__global__ void k_loopae2(const float* sumea_h,const float* sumea_t,const float* v_edge,
                          float* lae_h,float* lae_t,float invE){
  int side=blockIdx.x; int h=threadIdx.x; if(h>=2) return;
  const float* se = side? sumea_t : sumea_h;
  float* o = side? lae_t : lae_h;
  float acc=0.f;
  for(int f=0; f<64; f++) acc += se[f]*v_edge[h*64+f];
  o[h] = acc*invE;
}

template<typename TE>
static __device__ void eags_body(int idx,const float* gsum,const int* es,const int* ee,
                                 const void* W_lu,const void* b_lu,float* ea_gs){
  int g=idx>>6, f=idx&63;
  float acc=0.f;
  for(int k=0;k<64;k++) acc += gsum[g*64+k]*ldv<TE>(W_lu,f*64+k);
  float cnt=(float)(ee[g]-es[g]);
  ea_gs[idx]=acc + cnt*ldv<TE>(b_lu,f);
}
__global__ void k_ea_gs(const int* dflag,const float* gsum_h,const float* gsum_t,
                        const int* es_h,const int* ee_h,const int* es_t,const int* ee_t,
                        const void* W_lu,const void* b_lu,float* eags_h,float* eags_t){
  int idx = blockIdx.x*blockDim.x + threadIdx.x;
  if(idx>=G_*64) return;
  int side=blockIdx.y;
  const float* gsum = side? gsum_t : gsum_h;
  const int* es = side? es_t : es_h;
  const int* ee = side? ee_t : ee_h;
  float* eags = side? eags_t : eags_h;
  if(*dflag) eags_body<float>(idx,gsum,es,ee,W_lu,b_lu,eags);
  else       eags_body<bf16 >(idx,gsum,es,ee,W_lu,b_lu,eags);
}

template<typename TE>
static __device__ void hge_body(int idx,const float* ea_gs,const void* W_re,const void* b_re,float* hge){
  int g=idx>>7, o=idx&127;
  float acc=0.f;
  for(int f=0;f<64;f++) acc += ea_gs[g*64+f]*ldv<TE>(W_re,(size_t)o*64+f);
  acc += ldv<TE>(b_re,o);
  hge[idx]=acc>0.f?acc:0.f;
}
__global__ void k_hge(const int* dflag,const float* eags_h,const float* eags_t,
                      const void* W_re,const void* b_re,float* hge_h,float* hge_t){
  int idx = blockIdx.x*blockDim.x + threadIdx.x;
  if(idx>=G_*128) return;
  int side=blockIdx.y;
  const float* eags = side? eags_t : eags_h;
  float* hge = side? hge_t : hge_h;
  if(*dflag) hge_body<float>(idx,eags,W_re,b_re,hge);
  else       hge_body<bf16 >(idx,eags,W_re,b_re,hge);
}

// ---------------- per-node alphas for stage A (both sides via grid.y) ----------------
__global__ void k_node_alpha1(const int* dflag,const void* x_h,const void* x_t,
                              const float* __restrict__ cva,const float* __restrict__ cvb,
                              float* a1s_h,float* a1d_h,float* a1s_t,float* a1d_t){
  int i = blockIdx.x*blockDim.x + threadIdx.x;
  if(i>=N_) return;
  int side=blockIdx.y;
  const void* X = side? x_t : x_h;
  float* oa = side? a1s_t : a1s_h;
  float* ob = side? a1d_t : a1d_h;
  float a0=0,a1=0,b0=0,b1=0;
  if(*dflag){
    const float* x=(const float*)X + (size_t)i*64;
    for(int k=0;k<64;k++){ float v=x[k]; a0+=v*cva[k]; a1+=v*cva[64+k]; b0+=v*cvb[k]; b1+=v*cvb[64+k]; }
  } else {
    const bf16* x=(const bf16*)X + (size_t)i*64;
    for(int k=0;k<64;k++){ float v=b2f(x[k]); a0+=v*cva[k]; a1+=v*cva[64+k]; b0+=v*cvb[k]; b1+=v*cvb[64+k]; }
  }
  oa[i*2]=a0; oa[i*2+1]=a1; ob[i*2]=b0; ob[i*2+1]=b1;
}

// ---------------- stage-A edge alpha (with edge attr), both sides via grid.y ----------------
__global__ void k_edge_alpha1(const int* dflag,
                              const float* a1s_h,const float* a1d_h,
                              const float* a1s_t,const float* a1d_t,
                              const int* ei_h,const int* ei_t,
                              const void* eat_h,const void* eat_t,
                              const float* __restrict__ vedge,
                              const float* lae_h,const float* lae_t,
                              float* alpha_h,float* alpha_t){
  __shared__ float sv[128];
  int t = threadIdx.x;
  if(t<128) sv[t]=vedge[t];
  __syncthreads();
  int side=blockIdx.y;
  const float* asrc = side? a1s_t : a1s_h;
  const float* adst = side? a1d_t : a1d_h;
  const int* srcI = side? ei_t : ei_h;
  const int* dstI = srcI + E_;
  const void* eattr = side? eat_t : eat_h;
  const float* loopae = side? lae_t : lae_h;
  float* alpha = side? alpha_t : alpha_h;
  int e = blockIdx.x*blockDim.x + t;
  if(e>=E_+N_) return;
  int s,d; float ae0=0.f, ae1=0.f;
  if(e<E_){
    s=srcI[e]; d=dstI[e];
    if(*dflag){
      const float4* row=(const float4*)((const float*)eattr + (size_t)e*64);
      #pragma unroll
      for(int k=0;k<16;k++){
        float4 v=row[k];
        ae0 += v.x*sv[4*k]   + v.y*sv[4*k+1]   + v.z*sv[4*k+2]   + v.w*sv[4*k+3];
        ae1 += v.x*sv[64+4*k]+ v.y*sv[64+4*k+1]+ v.z*sv[64+4*k+2]+ v.w*sv[64+4*k+3];
      }
    } else {
      const uint4* row=(const uint4*)((const bf16*)eattr + (size_t)e*64);
      #pragma unroll
      for(int k=0;k<8;k++){
        uint4 u=row[k];
        float f0=bfu(u.x&0xffffu), f1=bfu(u.x>>16), f2=bfu(u.y&0xffffu), f3=bfu(u.y>>16);
        float f4=bfu(u.z&0xffffu), f5=bfu(u.z>>16), f6=bfu(u.w&0xffffu), f7=bfu(u.w>>16);
        ae0 += f0*sv[8*k]+f1*sv[8*k+1]+f2*sv[8*k+2]+f3*sv[8*k+3]
             + f4*sv[8*k+4]+f5*sv[8*k+5]+f6*sv[8*k+6]+f7*sv[8*k+7];
        ae1 += f0*sv[64+8*k]+f1*sv[64+8*k+1]+f2*sv[64+8*k+2]+f3*sv[64+8*k+3]
             + f4*sv[64+8*k+4]+f5*sv[64+8*k+5]+f6*sv[64+8*k+6]+f7*sv[64+8*k+7];
      }
    }
  } else {
    s=d=e-E_;
    ae0=loopae[0]; ae1=loopae[1];
  }
  float l0 = asrc[s*2]  +adst[d*2]  +ae0; l0 = l0>0.f? l0 : 0.2f*l0;
  float l1 = asrc[s*2+1]+adst[d*2+1]+ae1; l1 = l1>0.f? l1 : 0.2f*l1;
  alpha[e*2]  = expf(fminf(l0,50.f));
  alpha[e*2+1]= expf(fminf(l1,50.f));
}

// ---------------- stage-2 edge alphas (4 jobs via grid.y, no edge attr) ----------------
__global__ void k_edge_alpha2(const float* ais_h,const float* aid_h,
                              const float* ais_t,const float* aid_t,
                              const float* abs_h,const float* abd_h,
                              const float* abs_t,const float* abd_t,
                              const int* ei_h,const int* ei_t,const int* bei,
                              float* a_ih,float* a_it,float* a_bt,float* a_bh){
  int e = blockIdx.x*blockDim.x + threadIdx.x;
  if(e>=E_+N_) return;
  int y = blockIdx.y;
  const float *asrc,*adst; const int *srcI,*dstI; float* alpha;
  if(y==0){ asrc=ais_h; adst=aid_h; srcI=ei_h;    dstI=ei_h+E_;  alpha=a_ih; }
  else if(y==1){ asrc=ais_t; adst=aid_t; srcI=ei_t; dstI=ei_t+E_; alpha=a_it; }
  else if(y==2){ asrc=abs_h; adst=abd_t; srcI=bei;  dstI=bei+EBI; alpha=a_bt; }
  else { asrc=abs_t; adst=abd_h; srcI=bei+EBI; dstI=bei; alpha=a_bh; }
  int s,d;
  if(e<E_){ s=srcI[e]; d=dstI[e]; } else { s=d=e-E_; }
  float l0 = asrc[s*2]  +adst[d*2];   l0 = l0>0.f? l0 : 0.2f*l0;
  float l1 = asrc[s*2+1]+adst[d*2+1]; l1 = l1>0.f? l1 : 0.2f*l1;
  alpha[e*2]  = expf(fminf(l0,50.f));
  alpha[e*2+1]= expf(fminf(l1,50.f));
}

// ---------------- stage-A gather (both sides via grid.y) ----------------
__global__ __launch_bounds__(256) void k_gatherA(const int* dflag,
    const void* x_h,const void* x_t,
    const float* alpha_h,const float* alpha_t,
    const int* rp0,const int* eid0,const int* src0,
    const int* rp1,const int* eid1,const int* src1,
    float* C,float* D){
  int t=threadIdx.x, side=blockIdx.y;
  int d=blockIdx.x*2 + (t>>7);
  if(d>=N_) return;
  const void* X = side? x_t : x_h;
  const float* alpha = side? alpha_t : alpha_h;
  const int* rp  = side? rp1  : rp0;
  const int* eid = side? eid1 : eid0;
  const int* src = side? src1 : src0;
  float* out = side? D : C;
  int ch=t&127, h=ch>>6, f=ch&63;
  int f32=*dflag;
  int j0=rp[d], j1=rp[d+1];
  float acc=0.f, ss=0.f;
  for(int j=j0;j<j1;j++){
    int e=eid[j], s=src[j];
    float a=alpha[(size_t)e*2+h];
    float xv = f32? ((const float*)X)[(size_t)s*64+f] : b2f(((const bf16*)X)[(size_t)s*64+f]);
    acc+=xv*a; ss+=a;
  }
  {
    float a=alpha[((size_t)E_+d)*2+h];
    float xv = f32? ((const float*)X)[(size_t)d*64+f] : b2f(((const bf16*)X)[(size_t)d*64+f]);
    acc+=xv*a; ss+=a;
  }
  out[(size_t)d*128+ch]=acc/(ss+1e-16f);
}

// per-head transform of stage-A accumulator + bias + ELU (register-tiled)
// grid: (ceil(N/64), half, side)
__global__ __launch_bounds__(256) void k_headelu(const int* dflag,
    const float* __restrict__ C,const float* __restrict__ D,
    const void* W, const void* bias, bf16* eh, bf16* et){
  __shared__ float sA[64*68];
  __shared__ float sW[64*68];
  __shared__ float sB[64];
  const int t = threadIdx.x;
  const int half = blockIdx.y;
  const int side = blockIdx.z;
  const int n0 = blockIdx.x*64;
  const int f32 = *dflag;
  const float* acc = side? D : C;
  bf16* out = side? et : eh;
  for(int i=t;i<4096;i+=256){
    int o=i>>6, k=i&63;
    float v = f32 ? ((const float*)W)[(size_t)(half*64+o)*64+k]
                  : b2f(((const bf16*)W)[(size_t)(half*64+o)*64+k]);
    int om = (o>>2) | ((o&3)<<4);
    sW[om*68+k] = v;
  }
  if(t<64) sB[t] = f32 ? ((const float*)bias)[half*64+t] : b2f(((const bf16*)bias)[half*64+t]);
  for(int i=t;i<1024;i+=256){
    int m=i>>4, k4=i&15;
    int n=n0+m;
    float4 v = make_float4(0.f,0.f,0.f,0.f);
    if(n<N_) v = *(const float4*)&acc[((size_t)(2*n+half))*64 + k4*4];
    *(float4*)&sA[m*68 + k4*4] = v;
  }
  __syncthreads();
  const int cg = t&15, rg = t>>4;
  float s[4][4];
  #pragma unroll
  for(int i=0;i<4;i++)
    #pragma unroll
    for(int j=0;j<4;j++) s[i][j]=0.f;
  #pragma unroll 4
  for(int k0=0;k0<64;k0+=4){
    float4 a[4], w[4];
    #pragma unroll
    for(int i=0;i<4;i++) a[i] = *(const float4*)&sA[(rg+16*i)*68 + k0];
    #pragma unroll
    for(int j=0;j<4;j++) w[j] = *(const float4*)&sW[(cg+16*j)*68 + k0];
    #pragma unroll
    for(int i=0;i<4;i++)
      #pragma unroll
      for(int j=0;j<4;j++)
        s[i][j] += a[i].x*w[j].x + a[i].y*w[j].y + a[i].z*w[j].z + a[i].w*w[j].w;
  }
  #pragma unroll
  for(int i=0;i<4;i++){
    int n = n0 + rg + 16*i;
    if(n>=N_) continue;
    union { bf16 h[4]; uint2 u; } pk;
    #pragma unroll
    for(int j=0;j<4;j++){
      float v = s[i][j] + sB[4*cg+j];
      v = v>0.f ? v : expf(v)-1.f;
      pk.h[j] = f2b(v);
    }
    *(uint2*)&out[((size_t)(2*n+half))*64 + 4*cg] = pk.u;
  }
}

// ---------------- fused: msgI/msgB GEMMs + 8 stage-2 alpha dots (per side) ----------------
__global__ __launch_bounds__(256) void k_msg_alpha(const int* dflag,
    const bf16* __restrict__ eh, const bf16* __restrict__ et,
    const void* W_i, const void* W_bs,
    const float* c_i_s,const float* c_i_d,const float* c_b_s,const float* c_b_d,
    bf16* msgI_h,bf16* msgI_t,bf16* msgB_h,bf16* msgB_t,
    float* ais_h,float* aid_h,float* abs_h,float* abd_h,
    float* ais_t,float* aid_t,float* abs_t,float* abd_t){
  __shared__ float sA[64*132];
  __shared__ float sW[64*68];
  __shared__ float scv[8*132];
  int t=threadIdx.x, side=blockIdx.y;
  int n0=blockIdx.x*64;
  const bf16* X = side? et : eh;
  bf16* msgI = side? msgI_t : msgI_h;
  bf16* msgB = side? msgB_t : msgB_h;
  float* ais = side? ais_t : ais_h;
  float* aid = side? aid_t : aid_h;
  float* ab_s = side? abs_t : abs_h;
  float* ab_d = side? abd_t : abd_h;
  int f32=*dflag;
  // stage A rows (bf16 -> f32), zero-fill OOB
  for(int i=t;i<512;i+=256){
    int m=i>>3, c16=(i&7)*16;
    int n=n0+m;
    float v[16];
    if(n<N_){
      uint4 u0=*(const uint4*)(X+(size_t)n*128+c16);
      uint4 u1=*(const uint4*)(X+(size_t)n*128+c16+8);
      v[0]=bfu(u0.x&0xffffu); v[1]=bfu(u0.x>>16); v[2]=bfu(u0.y&0xffffu); v[3]=bfu(u0.y>>16);
      v[4]=bfu(u0.z&0xffffu); v[5]=bfu(u0.z>>16); v[6]=bfu(u0.w&0xffffu); v[7]=bfu(u0.w>>16);
      v[8]=bfu(u1.x&0xffffu); v[9]=bfu(u1.x>>16); v[10]=bfu(u1.y&0xffffu); v[11]=bfu(u1.y>>16);
      v[12]=bfu(u1.z&0xffffu); v[13]=bfu(u1.z>>16); v[14]=bfu(u1.w&0xffffu); v[15]=bfu(u1.w>>16);
    } else {
      #pragma unroll
      for(int q=0;q<16;q++) v[q]=0.f;
    }
    #pragma unroll
    for(int q=0;q<16;q++) sA[m*132+c16+q]=v[q];
  }
  // stage combined attention vectors
  for(int i=t;i<1024;i+=256){
    int v=i>>7, k=i&127;
    const float* s = (v<2)? c_i_s : (v<4)? c_i_d : (v<6)? c_b_s : c_b_d;
    scv[v*132+k] = s[(v&1)*128+k];
  }
  __syncthreads();
  // 8 alpha dots per row
  #pragma unroll
  for(int it=0;it<2;it++){
    int task=t+it*256;
    int row=task>>3, v=task&7;
    int n=n0+row;
    float acc=0.f;
    for(int k=0;k<128;k++) acc += sA[row*132+k]*scv[v*132+k];
    if(n<N_){
      float* o = (v<2)? ais : (v<4)? aid : (v<6)? ab_s : ab_d;
      o[(size_t)n*2+(v&1)]=acc;
    }
  }
  // two O=64 GEMMs sharing sA
  const int cg=t&15, rg=t>>4;
  for(int chunk=0;chunk<2;chunk++){
    const void* W = chunk? W_bs : W_i;
    bf16* out = chunk? msgB : msgI;
    float s[4][4];
    #pragma unroll
    for(int i=0;i<4;i++)
      #pragma unroll
      for(int j=0;j<4;j++) s[i][j]=0.f;
    for(int kc=0;kc<128;kc+=64){
      __syncthreads();
      for(int i=t;i<4096;i+=256){
        int o=i>>6,k=i&63;
        float v = f32? ((const float*)W)[(size_t)o*128+kc+k] : b2f(((const bf16*)W)[(size_t)o*128+kc+k]);
        int om=(o>>2)|((o&3)<<4);
        sW[om*68+k]=v;
      }
      __syncthreads();
      #pragma unroll 4
      for(int k0=0;k0<64;k0+=4){
        float4 a[4], w[4];
        #pragma unroll
        for(int i=0;i<4;i++) a[i] = *(const float4*)&sA[(rg+16*i)*132 + kc + k0];
        #pragma unroll
        for(int j=0;j<4;j++) w[j] = *(const float4*)&sW[(cg+16*j)*68 + k0];
        #pragma unroll
        for(int i=0;i<4;i++)
          #pragma unroll
          for(int j=0;j<4;j++)
            s[i][j] += a[i].x*w[j].x + a[i].y*w[j].y + a[i].z*w[j].z + a[i].w*w[j].w;
      }
    }
    #pragma unroll
    for(int i=0;i<4;i++){
      int n = n0 + rg + 16*i;
      if(n>=N_) continue;
      union { bf16 h[4]; uint2 u; } pk;
      #pragma unroll
      for(int j=0;j<4;j++) pk.h[j]=f2b(s[i][j]);
      *(uint2*)&out[(size_t)n*64 + 4*cg] = pk.u;
    }
  }
}

// ---------------- fused stage-2 gather + rep + z/score dots ----------------
// grid: (N/2, side); 256 threads = 2 dst x 128 ch; wave = (dst,half)
__global__ __launch_bounds__(256) void k_gather_rep(const int* dflag,
    const bf16* msgI_h,const bf16* msgI_t,const bf16* msgB_h,const bf16* msgB_t,
    const float* a_ih,const float* a_it,const float* a_bt,const float* a_bh,
    const int* rp0,const int* eid0,const int* src0,
    const int* rp1,const int* eid1,const int* src1,
    const int* rp2,const int* eid2,const int* src2,
    const int* rp3,const int* eid3,const int* src3,
    const void* b_intra,const void* b_inter,
    const void* W_rel,const void* b_rel,const void* W_root,
    float* h_rep,float* t_rep,
    float* z_h,float* z_t,float* sc_h,float* sc_t){
  int t=threadIdx.x, side=blockIdx.y;
  int d=blockIdx.x*2 + (t>>7);
  int ch=t&127, half=ch>>6, ch64=ch&63, hh=ch64>>5;
  const bf16* msg; const float* alpha; const int *rp,*eid,*src; const void* bias;
  float *rep,*z,*sc;
  if(side==0){
    rep=h_rep; z=z_h; sc=sc_h;
    if(half==0){ msg=msgI_h; alpha=a_ih; rp=rp0; eid=eid0; src=src0; bias=b_intra; }
    else       { msg=msgB_t; alpha=a_bh; rp=rp3; eid=eid3; src=src3; bias=b_inter; }
  } else {
    rep=t_rep; z=z_t; sc=sc_t;
    if(half==0){ msg=msgI_t; alpha=a_it; rp=rp1; eid=eid1; src=src1; bias=b_intra; }
    else       { msg=msgB_h; alpha=a_bt; rp=rp2; eid=eid2; src=src2; bias=b_inter; }
  }
  int f32=*dflag;
  float repv=0.f;
  if(d<N_){
    int j0=rp[d], j1=rp[d+1];
    float acc=0.f, ss=0.f;
    for(int j=j0;j<j1;j++){
      int e=eid[j], s=src[j];
      float a=alpha[(size_t)e*2+hh];
      acc += b2f(msg[(size_t)s*64+ch64])*a; ss+=a;
    }
    float a=alpha[((size_t)E_+d)*2+hh];
    acc += b2f(msg[(size_t)d*64+ch64])*a; ss+=a;
    float b = f32? ((const float*)bias)[ch64] : b2f(((const bf16*)bias)[ch64]);
    repv = acc/(ss+1e-16f)+b;
    rep[(size_t)d*128+ch]=repv;
  }
  float wrel = f32? ((const float*)W_rel)[ch] : b2f(((const bf16*)W_rel)[ch]);
  float wroot= f32? ((const float*)W_root)[ch]: b2f(((const bf16*)W_root)[ch]);
  __shared__ float sz[256], sr[256];
  sz[t]=repv*wrel; sr[t]=repv*wroot;
  __syncthreads();
  for(int w=64;w>0;w>>=1){
    if((t&127)<w){ sz[t]+=sz[t+w]; sr[t]+=sr[t+w]; }
    __syncthreads();
  }
  if((t&127)==0 && d<N_){
    float br = f32? ((const float*)b_rel)[0] : b2f(((const bf16*)b_rel)[0]);
    z[d]=sz[t];
    sc[d]=sr[t]+br;
  }
}

// score[d] += sum of z over incoming real edges (CSR, no atomics)
__global__ void k_score_gather(const float* z_h,const float* z_t,
    const int* rp0,const int* src0,const int* rp1,const int* src1,
    float* sc_h,float* sc_t){
  int i = blockIdx.x*blockDim.x + threadIdx.x;
  if(i>=N_) return;
  int side=blockIdx.y;
  const float* z = side? z_t : z_h;
  const int* rp = side? rp1 : rp0;
  const int* sr = side? src1 : src0;
  float* sc = side? sc_t : sc_h;
  float a=0.f;
  for(int j=rp[i];j<rp[i+1];j++) a += z[sr[j]];
  sc[i]+=a;
}

// ---------------- fused SAG readout + graph LayerNorm ----------------
__global__ __launch_bounds__(128) void k_finalize(const int* dflag,
    const float* __restrict__ h_rep,const float* __restrict__ t_rep,
    const float* __restrict__ sc_h,const float* __restrict__ sc_t,
    const int* ns_h,const int* ne_h,const int* ns_t,const int* ne_t,
    const float* __restrict__ hge_h,const float* __restrict__ hge_t,
    const void* lnw,const void* lnb,
    void* out,size_t o_hg,size_t o_tg,size_t o_hx,size_t o_tx){
  int g=blockIdx.x, side=blockIdx.y, tid=threadIdx.x;
  const float* rep = side? t_rep : h_rep;
  const float* sc  = side? sc_t  : sc_h;
  const float* hge = side? hge_t : hge_h;
  int s = side? ns_t[g] : ns_h[g];
  int e = side? ne_t[g] : ne_h[g];
  size_t og = side? o_tg : o_hg;
  size_t ox = side? o_tx : o_hx;
  __shared__ float red[128];
  float m=-1e30f;
  for(int n=s+tid;n<e;n+=128) m=fmaxf(m,sc[n]);
  red[tid]=m; __syncthreads();
  for(int w=64;w>0;w>>=1){ if(tid<w) red[tid]=fmaxf(red[tid],red[tid+w]); __syncthreads(); }
  float M=red[0]; __syncthreads();
  float den=0.f;
  for(int n=s+tid;n<e;n+=128) den += expf(sc[n]-M);
  red[tid]=den; __syncthreads();
  for(int w=64;w>0;w>>=1){ if(tid<w) red[tid]+=red[tid+w]; __syncthreads(); }
  den=red[0]; __syncthreads();
  float sm=0.f,sq=0.f;
  for(int n=s;n<e;n++){ float v=rep[(size_t)n*128+tid]; sm+=v; sq+=v*v; }
  red[tid]=sm; __syncthreads();
  for(int w=64;w>0;w>>=1){ if(tid<w) red[tid]+=red[tid+w]; __syncthreads(); }
  float S=red[0]; __syncthreads();
  red[tid]=sq; __syncthreads();
  for(int w=64;w>0;w>>=1){ if(tid<w) red[tid]+=red[tid+w]; __syncthreads(); }
  float SQ=red[0];
  float cntf=(float)(e-s);
  float norm=(cntf>1.f?cntf:1.f)*128.f;
  float mean=S/norm;
  float var=SQ/norm-mean*mean; var=var>0.f?var:0.f;
  float inv=rsqrtf(var+1e-5f);
  int f32=*dflag;
  float wf,bb;
  if(f32){ wf=((const float*)lnw)[tid]; bb=((const float*)lnb)[tid]; }
  else   { wf=b2f(((const bf16*)lnw)[tid]); bb=b2f(((const bf16*)lnb)[tid]); }
  float acc=0.f;
  for(int n=s;n<e;n++){
    float v=rep[(size_t)n*128+tid];
    acc += v*expf(sc[n]-M);
    float lv=(v-mean)*inv*wf+bb;
    lv = lv>0.f? lv : 0.f;
    if(f32) ((float*)out)[ox+(size_t)n*128+tid]=lv;
    else    ((bf16 *)out)[ox+(size_t)n*128+tid]=f2b(lv);
  }
  float v = acc/(den+1e-16f) + hge[(size_t)g*128+tid];
  if(f32) ((float*)out)[og+(size_t)g*128+tid]=v;
  else    ((bf16 *)out)[og+(size_t)g*128+tid]=f2b(v);
}

// ---------------- final relu(ea) dense: out = relu(eat @ W_lu^T + b_lu), both sides ----------------
__global__ __launch_bounds__(256) void k_ea_final(const int* dflag,
    const void* eat_h,const void* eat_t,
    const void* W,const void* bias,void* out,size_t off_h,size_t off_t){
  __shared__ float sA[64*68];
  __shared__ float sW[64*68];
  __shared__ float sB[64];
  const int t=threadIdx.x;
  const int side=blockIdx.y;
  const int n0=blockIdx.x*64;
  const int f32=*dflag;
  const void* A = side? eat_t : eat_h;
  size_t outOff = side? off_t : off_h;
  if(t<64) sB[t] = f32? ((const float*)bias)[t] : b2f(((const bf16*)bias)[t]);
  for(int i=t;i<4096;i+=256){
    int o=i>>6, k=i&63;
    float v = f32 ? ((const float*)W)[(size_t)o*64+k] : b2f(((const bf16*)W)[(size_t)o*64+k]);
    int om=(o>>2)|((o&3)<<4);
    sW[om*68+k]=v;
  }
  if(f32){
    for(int i=t;i<1024;i+=256){
      int m=i>>4, k4=(i&15)*4; int n=n0+m;
      float4 v = *(const float4*)((const float*)A + (size_t)n*64 + k4);
      *(float4*)&sA[m*68+k4] = v;
    }
  } else {
    for(int i=t;i<512;i+=256){
      int m=i>>3, k8=(i&7)*8; int n=n0+m;
      uint4 u = *(const uint4*)((const bf16*)A + (size_t)n*64 + k8);
      float4 v0, v1;
      v0.x=bfu(u.x&0xffffu); v0.y=bfu(u.x>>16); v0.z=bfu(u.y&0xffffu); v0.w=bfu(u.y>>16);
      v1.x=bfu(u.z&0xffffu); v1.y=bfu(u.z>>16); v1.z=bfu(u.w&0xffffu); v1.w=bfu(u.w>>16);
      *(float4*)&sA[m*68+k8]   = v0;
      *(float4*)&sA[m*68+k8+4] = v1;
    }
  }
  __syncthreads();
  const int cg=t&15, rg=t>>4;
  float s[4][4];
  #pragma unroll
  for(int i=0;i<4;i++)
    #pragma unroll
    for(int j=0;j<4;j++) s[i][j]=0.f;
  #pragma unroll 4
  for(int k0=0;k0<64;k0+=4){
    float4 a[4], w[4];
    #pragma unroll
    for(int i=0;i<4;i++) a[i] = *(const float4*)&sA[(rg+16*i)*68 + k0];
    #pragma unroll
    for(int j=0;j<4;j++) w[j] = *(const float4*)&sW[(cg+16*j)*68 + k0];
    #pragma unroll
    for(int i=0;i<4;i++)
      #pragma unroll
      for(int j=0;j<4;j++)
        s[i][j] += a[i].x*w[j].x + a[i].y*w[j].y + a[i].z*w[j].z + a[i].w*w[j].w;
  }
  #pragma unroll
  for(int i=0;i<4;i++){
    int n = n0 + rg + 16*i;
    float vv[4];
    #pragma unroll
    for(int j=0;j<4;j++){
      float v = s[i][j] + sB[4*cg+j];
      vv[j] = v>0.f? v : 0.f;
    }
    if(f32){
      float4 v4 = make_float4(vv[0],vv[1],vv[2],vv[3]);
      *(float4*)((float*)out + outOff + (size_t)n*64 + 4*cg) = v4;
    } else {
      union { bf16 h[4]; uint2 u; } pk;
      #pragma unroll
      for(int j=0;j<4;j++) pk.h[j]=f2b(vv[j]);
      *(uint2*)((bf16*)out + outOff + (size_t)n*64 + 4*cg) = pk.u;
    }
  }
}

extern "C" void kernel_launch(void* const* d_in, const int* in_sizes, int n_in,
                              void* d_out, int out_size, void* d_ws, size_t ws_size,
                              hipStream_t stream) {
  const void* x_h      = d_in[0];
  const void* x_t      = d_in[1];
  const void* eat_h    = d_in[2];
  const void* eat_t    = d_in[3];
  const int*  ei_h     = (const int*)d_in[4];
  const int*  ei_t     = (const int*)d_in[5];
  const int*  bei      = (const int*)d_in[6];
  const int*  batch_h  = (const int*)d_in[7];
  const int*  batch_t  = (const int*)d_in[8];
  const int*  ebat_h   = (const int*)d_in[9];
  const int*  ebat_t   = (const int*)d_in[10];
  const void* W_fc     = d_in[11];
  const void* a_s_fc   = d_in[12];
  const void* a_d_fc   = d_in[13];
  const void* W_e      = d_in[14];
  const void* a_e      = d_in[15];
  const void* b_fc     = d_in[16];
  const void* W_lu     = d_in[17];
  const void* b_lu     = d_in[18];
  const void* W_i      = d_in[19];
  const void* a_s_i    = d_in[20];
  const void* a_d_i    = d_in[21];
  const void* b_intra  = d_in[22];
  const void* W_bs     = d_in[23];
  const void* W_bd     = d_in[24];
  const void* a_s_b    = d_in[25];
  const void* a_d_b    = d_in[26];
  const void* b_inter  = d_in[27];
  const void* W_rel    = d_in[28];
  const void* b_rel    = d_in[29];
  const void* W_root   = d_in[30];
  const void* ln_w     = d_in[31];
  const void* ln_b     = d_in[32];
  const void* W_re     = d_in[33];
  const void* b_re     = d_in[34];

  // output element offsets (elements, in output dtype)
  const size_t o_hx  = 0;
  const size_t o_eah = (size_t)N_*128;
  const size_t o_tx  = o_eah + (size_t)E_*64;
  const size_t o_eat = o_tx  + (size_t)N_*128;
  const size_t o_hg  = o_eat + (size_t)E_*64;
  const size_t o_tg  = o_hg  + (size_t)G_*128;

  // ---- d_out as mid-pipeline scratch (bf16-indexed; all dead before final writes) ----
  bf16* eh   = (bf16*)d_out + o_hx;
  bf16* et   = (bf16*)d_out + o_tx;
  bf16* msgI_h = (bf16*)d_out + o_eah;
  bf16* msgI_t = msgI_h + (size_t)N_*64;
  bf16* msgB_h = msgI_h + (size_t)2*N_*64;
  bf16* msgB_t = msgI_h + (size_t)3*N_*64;
  float* areg  = (float*)((bf16*)d_out + o_eat);
  float* alpha1_h  = areg;
  float* alpha1_t  = areg + (size_t)(E_+N_)*2;
  float* alpha2_ih = areg + (size_t)2*(E_+N_)*2;
  float* alpha2_it = areg + (size_t)3*(E_+N_)*2;
  float* alpha2_bt = alpha1_h;   // alias: alpha1 dead before stage-2 bipartite
  float* alpha2_bh = alpha1_t;
  int* csr_base = (int*)(areg + (size_t)4*(E_+N_)*2);
  int* eids = csr_base;                     // 4 x E
  int* srcs = csr_base + (size_t)4*E_;      // 4 x E
  int* eid0 = eids;                 int* eid1 = eids + (size_t)E_;
  int* eid2 = eids + (size_t)2*E_;  int* eid3 = eids + (size_t)3*E_;
  int* src0 = srcs;                 int* src1 = srcs + (size_t)E_;
  int* src2 = srcs + (size_t)2*E_;  int* src3 = srcs + (size_t)3*E_;

  // ---------------- workspace arena ----------------
  char* p = (char*)d_ws;
  size_t off = 0;
  auto alloc = [&](size_t bytes)->char*{
    char* r = p + off; off += (bytes + 255) & ~(size_t)255; return r;
  };
  int* dflag=(int*)alloc(256);
  int* es_h = (int*)alloc(G_*4); int* ee_h = (int*)alloc(G_*4);
  int* es_t = (int*)alloc(G_*4); int* ee_t = (int*)alloc(G_*4);
  int* ns_h = (int*)alloc(G_*4); int* ne_h = (int*)alloc(G_*4);
  int* ns_t = (int*)alloc(G_*4); int* ne_t = (int*)alloc(G_*4);
  float* sumea_h = (float*)alloc(64*4);
  float* sumea_t = (float*)alloc(64*4);
  float* c_fc_s=(float*)alloc(128*4); float* c_fc_d=(float*)alloc(128*4);
  float* v_edge=(float*)alloc(128*4);
  float* c_i_s=(float*)alloc(256*4);  float* c_i_d=(float*)alloc(256*4);
  float* c_b_s=(float*)alloc(256*4);  float* c_b_d=(float*)alloc(256*4);
  float* lae_h=(float*)alloc(2*4);    float* lae_t=(float*)alloc(2*4);
  int* cnt    = (int*)alloc((size_t)4*N_*4);
  int* cur    = (int*)alloc((size_t)4*N_*4);
  int* rowptr = (int*)alloc((size_t)4*NP1*4);
  int* part   = (int*)alloc((size_t)4*SCAN_NB*4);
  float* a1s_h=(float*)alloc((size_t)N_*2*4); float* a1d_h=(float*)alloc((size_t)N_*2*4);
  float* a1s_t=(float*)alloc((size_t)N_*2*4); float* a1d_t=(float*)alloc((size_t)N_*2*4);
  float* ais_h=(float*)alloc((size_t)N_*2*4); float* aid_h=(float*)alloc((size_t)N_*2*4);
  float* ais_t=(float*)alloc((size_t)N_*2*4); float* aid_t=(float*)alloc((size_t)N_*2*4);
  float* abs_h=(float*)alloc((size_t)N_*2*4); float* abd_h=(float*)alloc((size_t)N_*2*4);
  float* abs_t=(float*)alloc((size_t)N_*2*4); float* abd_t=(float*)alloc((size_t)N_*2*4);
  float* z_h=(float*)alloc((size_t)N_*4); float* z_t=(float*)alloc((size_t)N_*4);
  float* sc_h=(float*)alloc((size_t)N_*4); float* sc_t=(float*)alloc((size_t)N_*4);
  float* gsum_h=(float*)alloc((size_t)G_*64*4); float* gsum_t=(float*)alloc((size_t)G_*64*4);
  float* eags_h=(float*)alloc((size_t)G_*64*4); float* eags_t=(float*)alloc((size_t)G_*64*4);
  float* hge_h =(float*)alloc((size_t)G_*128*4); float* hge_t =(float*)alloc((size_t)G_*128*4);
  float* C = (float*)alloc((size_t)N_*128*4);   // stage-A acc (h), then t_rep
  float* D = (float*)alloc((size_t)N_*128*4);   // stage-A acc (t), then h_rep
  float* t_rep = C;
  float* h_rep = D;

  int* rp0 = rowptr;                  int* rp1 = rowptr + (size_t)NP1;
  int* rp2 = rowptr + (size_t)2*NP1;  int* rp3 = rowptr + (size_t)3*NP1;

  auto cdiv=[](long a, long b){ return (int)((a+b-1)/b); };

  // ---------------- phase 0: probe, zero, setup ----------------
  k_detect<<<1,256,0,stream>>>(x_h, dflag);
  hipMemsetAsync(es_h, 0, (size_t)G_*4*8, stream);
  hipMemsetAsync(sumea_h, 0, 512, stream);
  hipMemsetAsync(cnt, 0, (size_t)4*N_*4, stream);

  k_combine<<<6,256,0,stream>>>(dflag, W_fc,a_s_fc,a_d_fc, W_e,a_e, W_i,a_s_i,a_d_i,
                                W_bs,W_bd,a_s_b,a_d_b,
                                c_fc_s,c_fc_d,v_edge,c_i_s,c_i_d,c_b_s,c_b_d);
  k_ranges4<<<dim3(cdiv(E_,256),4),256,0,stream>>>(ebat_h,ebat_t,batch_h,batch_t,
                                es_h,ee_h,es_t,ee_t,ns_h,ne_h,ns_t,ne_t);

  // ---------------- CSR build ----------------
  k_hist4<<<dim3(cdiv(E_,256),4),256,0,stream>>>(ei_h, ei_t, bei, cnt);
  k_scan1<<<dim3(SCAN_NB,4),256,0,stream>>>(cnt, rowptr, part);
  k_scan2<<<4,32,0,stream>>>(part, rowptr);
  k_scan3<<<dim3(SCAN_NB,4),256,0,stream>>>(rowptr, part, cur);
  k_fill4<<<dim3(cdiv(E_,256),4),256,0,stream>>>(ei_h, ei_t, bei, cur, eids, srcs);

  // ---------------- edge-graph pooling path ----------------
  k_graph_easum<<<dim3(G_,2),256,0,stream>>>(dflag, eat_h,eat_t, es_h,ee_h,es_t,ee_t,
                                gsum_h,gsum_t, sumea_h,sumea_t);
  k_loopae2<<<2,64,0,stream>>>(sumea_h, sumea_t, v_edge, lae_h, lae_t, 1.f/(float)E_);
  k_ea_gs<<<dim3(cdiv(G_*64,256),2),256,0,stream>>>(dflag, gsum_h,gsum_t,
                                es_h,ee_h,es_t,ee_t, W_lu, b_lu, eags_h, eags_t);
  k_hge<<<dim3(cdiv(G_*128,256),2),256,0,stream>>>(dflag, eags_h, eags_t, W_re, b_re, hge_h, hge_t);

  // ---------------- stage A: feature GATConv ----------------
  k_node_alpha1<<<dim3(cdiv(N_,256),2),256,0,stream>>>(dflag, x_h, x_t, c_fc_s, c_fc_d,
                                a1s_h, a1d_h, a1s_t, a1d_t);
  k_edge_alpha1<<<dim3(cdiv(E_+N_,256),2),256,0,stream>>>(dflag, a1s_h,a1d_h,a1s_t,a1d_t,
                                ei_h, ei_t, eat_h, eat_t, v_edge, lae_h, lae_t,
                                alpha1_h, alpha1_t);
  k_gatherA<<<dim3(cdiv(N_,2),2),256,0,stream>>>(dflag, x_h, x_t, alpha1_h, alpha1_t,
                                rp0, eid0, src0, rp1, eid1, src1, C, D);
  k_headelu<<<dim3(cdiv(N_,64),2,2),256,0,stream>>>(dflag, C, D, W_fc, b_fc, eh, et);

  // ---------------- stage 2: fused message transforms + alphas ----------------
  k_msg_alpha<<<dim3(cdiv(N_,64),2),256,0,stream>>>(dflag, eh, et, W_i, W_bs,
                                c_i_s, c_i_d, c_b_s, c_b_d,
                                msgI_h, msgI_t, msgB_h, msgB_t,
                                ais_h, aid_h, abs_h, abd_h,
                                ais_t, aid_t, abs_t, abd_t);
  k_edge_alpha2<<<dim3(cdiv(E_+N_,256),4),256,0,stream>>>(ais_h,aid_h,ais_t,aid_t,
                                abs_h,abd_h,abs_t,abd_t, ei_h, ei_t, bei,
                                alpha2_ih, alpha2_it, alpha2_bt, alpha2_bh);

  // ---------------- stage 2: gather + rep + z/score ----------------
  k_gather_rep<<<dim3(cdiv(N_,2),2),256,0,stream>>>(dflag,
                                msgI_h, msgI_t, msgB_h, msgB_t,
                                alpha2_ih, alpha2_it, alpha2_bt, alpha2_bh,
                                rp0, eid0, src0, rp1, eid1, src1,
                                rp2, eid2, src2, rp3, eid3, src3,
                                b_intra, b_inter, W_rel, b_rel, W_root,
                                h_rep, t_rep, z_h, z_t, sc_h, sc_t);
  k_score_gather<<<dim3(cdiv(N_,256),2),256,0,stream>>>(z_h, z_t, rp0, src0, rp1, src1, sc_h, sc_t);

  // ---------------- fused readout + LN ----------------
  k_finalize<<<dim3(G_,2),128,0,stream>>>(dflag, h_rep, t_rep, sc_h, sc_t,
                                ns_h, ne_h, ns_t, ne_t, hge_h, hge_t,
                                ln_w, ln_b, d_out, o_hg, o_tg, o_hx, o_tx);

  // ---------------- final: relu(ea) outputs ----------------
  k_ea_final<<<dim3(E_/64,2),256,0,stream>>>(dflag, eat_h, eat_t, W_lu, b_lu,
                                d_out, o_eah, o_eat);

  (void)in_sizes; (void)n_in; (void)out_size; (void)ws_size;
}

// Round 4
// 1604.566 us; speedup vs baseline: 2.4115x; 1.2308x over previous
//
#include <hip/hip_runtime.h>
#include <hip/hip_bf16.h>

typedef __hip_bfloat16 bf16;

#define N_  100000
#define E_  400000
#define EBI 400000
#define G_  2048
#define NP1 (N_+1)
#define SCAN_B 1024
#define SCAN_NB ((N_+SCAN_B-1)/SCAN_B)

static __device__ __forceinline__ float b2f(bf16 v){ return __bfloat162float(v); }
static __device__ __forceinline__ bf16  f2b(float v){ return __float2bfloat16(v); }
static __device__ __forceinline__ float bfu(unsigned int u){
  union{unsigned int i; float f;} x; x.i = u<<16; return x.f;
}

template<typename T> static __device__ __forceinline__ float ldv(const void* p, size_t i){
  return (float)((const T*)p)[i];
}

// ---------------- dtype probe ----------------
__global__ void k_detect(const void* x, int* flag){
  __shared__ int cnt;
  if(threadIdx.x==0) cnt=0;
  __syncthreads();
  float v = fabsf(b2f(((const bf16*)x)[(size_t)threadIdx.x*2]));
  if(v>1e-3f && v<16.f) atomicAdd(&cnt,1);
  __syncthreads();
  if(threadIdx.x==0) *flag = (cnt<128) ? 1 : 0;   // 1 = external tensors are f32
}

// ---------------- combined attention vectors ----------------
template<typename TE>
static __device__ void combine_body(int idx,
    const void* W_fc,const void* a_s_fc,const void* a_d_fc,
    const void* W_e,const void* a_e,
    const void* W_i,const void* a_s_i,const void* a_d_i,
    const void* W_bs,const void* W_bd,const void* a_s_b,const void* a_d_b,
    float* c_fc_s,float* c_fc_d,float* v_edge,
    float* c_i_s,float* c_i_d,float* c_b_s,float* c_b_d){
  if(idx<384){
    int which=idx>>7; int r=idx&127; int h=r>>6, f=r&63;
    const void* W   = (which==2)? W_e : W_fc;
    const void* att = (which==0)? a_s_fc : (which==1)? a_d_fc : a_e;
    float acc=0.f;
    for(int c=0;c<64;c++) acc += ldv<TE>(W,(size_t)(h*64+c)*64+f)*ldv<TE>(att,h*64+c);
    ((which==0)? c_fc_s : (which==1)? c_fc_d : v_edge)[r]=acc;
  } else if(idx<1408){
    int t=idx-384; int which=t>>8; int r=t&255; int h=r>>7, f=r&127;
    const void* W   = (which<=1)? W_i : (which==2)? W_bs : W_bd;
    const void* att = (which==0)? a_s_i : (which==1)? a_d_i : (which==2)? a_s_b : a_d_b;
    float acc=0.f;
    for(int c=0;c<32;c++) acc += ldv<TE>(W,(size_t)(h*32+c)*128+f)*ldv<TE>(att,h*32+c);
    ((which==0)? c_i_s:(which==1)? c_i_d:(which==2)? c_b_s:c_b_d)[r]=acc;
  }
}
__global__ void k_combine(const int* dflag,
    const void* W_fc,const void* a_s_fc,const void* a_d_fc,
    const void* W_e,const void* a_e,
    const void* W_i,const void* a_s_i,const void* a_d_i,
    const void* W_bs,const void* W_bd,const void* a_s_b,const void* a_d_b,
    float* c_fc_s,float* c_fc_d,float* v_edge,
    float* c_i_s,float* c_i_d,float* c_b_s,float* c_b_d){
  int idx = blockIdx.x*blockDim.x + threadIdx.x;
  if(*dflag) combine_body<float>(idx,W_fc,a_s_fc,a_d_fc,W_e,a_e,W_i,a_s_i,a_d_i,W_bs,W_bd,a_s_b,a_d_b,
                                 c_fc_s,c_fc_d,v_edge,c_i_s,c_i_d,c_b_s,c_b_d);
  else       combine_body<bf16 >(idx,W_fc,a_s_fc,a_d_fc,W_e,a_e,W_i,a_s_i,a_d_i,W_bs,W_bd,a_s_b,a_d_b,
                                 c_fc_s,c_fc_d,v_edge,c_i_s,c_i_d,c_b_s,c_b_d);
}

// ---------------- sorted-segment ranges (4 jobs via grid.y) ----------------
__global__ void k_ranges4(const int* __restrict__ ebat_h,const int* __restrict__ ebat_t,
                          const int* __restrict__ batch_h,const int* __restrict__ batch_t,
                          int* es_h,int* ee_h,int* es_t,int* ee_t,
                          int* ns_h,int* ne_h,int* ns_t,int* ne_t){
  int i = blockIdx.x*blockDim.x + threadIdx.x;
  int y = blockIdx.y;
  const int* batch; int n; int *st,*en;
  if(y==0){ batch=ebat_h; n=E_; st=es_h; en=ee_h; }
  else if(y==1){ batch=ebat_t; n=E_; st=es_t; en=ee_t; }
  else if(y==2){ batch=batch_h; n=N_; st=ns_h; en=ne_h; }
  else { batch=batch_t; n=N_; st=ns_t; en=ne_t; }
  if(i>=n) return;
  int b = batch[i];
  if(i==0 || batch[i-1]!=b) st[b]=i;
  if(i==n-1 || batch[i+1]!=b) en[b]=i+1;
}

// ---------------- CSR build (4 CSRs via grid.y) ----------------
__global__ void k_hist4(const int* __restrict__ ei_h,const int* __restrict__ ei_t,
                        const int* __restrict__ bei,int* cnt){
  int e = blockIdx.x*blockDim.x + threadIdx.x;
  if(e>=E_) return;
  int y = blockIdx.y;
  const int* dst = (y==0)? ei_h+E_ : (y==1)? ei_t+E_ : (y==2)? bei+EBI : bei;
  atomicAdd(&cnt[(size_t)y*N_ + dst[e]],1);
}

__global__ __launch_bounds__(256) void k_scan1(const int* __restrict__ cnt, int* rowptr, int* part){
  int g = blockIdx.y, b = blockIdx.x, t = threadIdx.x;
  const int* c = cnt + (size_t)g*N_;
  int* rp = rowptr + (size_t)g*NP1;
  int i0 = b*SCAN_B + t*4;
  int v[4];
  #pragma unroll
  for(int j=0;j<4;j++){ int i=i0+j; v[j] = (i<N_)? c[i] : 0; }
  int T = v[0]+v[1]+v[2]+v[3];
  __shared__ int sh[256];
  sh[t]=T; __syncthreads();
  int run=T;
  for(int o=1;o<256;o<<=1){
    int add = (t>=o)? sh[t-o] : 0;
    __syncthreads();
    run += add; sh[t]=run;
    __syncthreads();
  }
  int p = run - T;   // exclusive prefix for this thread
  #pragma unroll
  for(int j=0;j<4;j++){ int i=i0+j; if(i<N_) rp[i]=p; p+=v[j]; }
  if(t==255) part[g*SCAN_NB + b] = run;
}

__global__ void k_scan2(int* part, int* rowptr){
  int g = blockIdx.x;
  if(threadIdx.x) return;
  int* p = part + g*SCAN_NB;
  int run=0;
  for(int i=0;i<SCAN_NB;i++){ int t=p[i]; p[i]=run; run+=t; }
  rowptr[(size_t)g*NP1 + N_] = run;
}

__global__ __launch_bounds__(256) void k_scan3(int* rowptr, const int* __restrict__ part, int* cur){
  int g=blockIdx.y, b=blockIdx.x, t=threadIdx.x;
  int base = part[g*SCAN_NB+b];
  int i0 = b*SCAN_B + t*4;
  int* rp = rowptr + (size_t)g*NP1;
  int* cu = cur + (size_t)g*N_;
  #pragma unroll
  for(int j=0;j<4;j++){ int i=i0+j; if(i<N_){ int v=rp[i]+base; rp[i]=v; cu[i]=v; } }
}

// fill: srcs in CSR order; pos[e] = CSR slot of original edge e
__global__ void k_fill4(const int* __restrict__ ei_h,const int* __restrict__ ei_t,
                        const int* __restrict__ bei,int* cur,int* poss,int* srcs){
  int e = blockIdx.x*blockDim.x + threadIdx.x;
  if(e>=E_) return;
  int y = blockIdx.y;
  const int *s,*d;
  if(y==0){ s=ei_h; d=ei_h+E_; }
  else if(y==1){ s=ei_t; d=ei_t+E_; }
  else if(y==2){ s=bei; d=bei+EBI; }
  else { s=bei+EBI; d=bei; }
  int dd = d[e];
  int pos = atomicAdd(&cur[(size_t)y*N_+dd],1);
  srcs[(size_t)y*E_+pos]=s[e];
  poss[(size_t)y*E_+e]=pos;
}

// per-graph raw edge_attr column sums + global column sum (both sides via grid.y)
__global__ __launch_bounds__(256) void k_graph_easum(const int* dflag,
                              const void* eat_h,const void* eat_t,
                              const int* es_h,const int* ee_h,const int* es_t,const int* ee_t,
                              float* gsum_h,float* gsum_t,float* gl_h,float* gl_t){
  int g=blockIdx.x, t=threadIdx.x, side=blockIdx.y;
  const void* ea = side? eat_t : eat_h;
  int s = side? es_t[g] : es_h[g];
  int e = side? ee_t[g] : ee_h[g];
  float* gsum = side? gsum_t : gsum_h;
  float* gl   = side? gl_t : gl_h;
  int f=t&63, q=t>>6;
  float acc=0.f;
  if(*dflag){ for(int i=s+q;i<e;i+=4) acc += ((const float*)ea)[(size_t)i*64+f]; }
  else      { for(int i=s+q;i<e;i+=4) acc += b2f(((const bf16*)ea)[(size_t)i*64+f]); }
  __shared__ float red[256];
  red[t]=acc; __syncthreads();
  if(t<128) red[t]+=red[t+128];
  __syncthreads();
  if(t<64){
    float v = red[t]+red[t+64];
    gsum[(size_t)g*64+t]=v;
    atomicAdd(&gl[t], v);
  }
}

__global__ void k_loopae2(const float* sumea_h,const float* sumea_t,const float* v_edge,
                          float* lae_h,float* lae_t,float invE){
  int side=blockIdx.x; int h=threadIdx.x; if(h>=2) return;
  const float* se = side? sumea_t : sumea_h;
  float* o = side? lae_t : lae_h;
  float acc=0.f;
  for(int f=0; f<64; f++) acc += se[f]*v_edge[h*64+f];
  o[h] = acc*invE;
}

template<typename TE>
static __device__ void eags_body(int idx,const float* gsum,const int* es,const int* ee,
                                 const void* W_lu,const void* b_lu,float* ea_gs){
  int g=idx>>6, f=idx&63;
  float acc=0.f;
  for(int k=0;k<64;k++) acc += gsum[g*64+k]*ldv<TE>(W_lu,f*64+k);
  float cnt=(float)(ee[g]-es[g]);
  ea_gs[idx]=acc + cnt*ldv<TE>(b_lu,f);
}
__global__ void k_ea_gs(const int* dflag,const float* gsum_h,const float* gsum_t,
                        const int* es_h,const int* ee_h,const int* es_t,const int* ee_t,
                        const void* W_lu,const void* b_lu,float* eags_h,float* eags_t){
  int idx = blockIdx.x*blockDim.x + threadIdx.x;
  if(idx>=G_*64) return;
  int side=blockIdx.y;
  const float* gsum = side? gsum_t : gsum_h;
  const int* es = side? es_t : es_h;
  const int* ee = side? ee_t : ee_h;
  float* eags = side? eags_t : eags_h;
  if(*dflag) eags_body<float>(idx,gsum,es,ee,W_lu,b_lu,eags);
  else       eags_body<bf16 >(idx,gsum,es,ee,W_lu,b_lu,eags);
}

template<typename TE>
static __device__ void hge_body(int idx,const float* ea_gs,const void* W_re,const void* b_re,float* hge){
  int g=idx>>7, o=idx&127;
  float acc=0.f;
  for(int f=0;f<64;f++) acc += ea_gs[g*64+f]*ldv<TE>(W_re,(size_t)o*64+f);
  acc += ldv<TE>(b_re,o);
  hge[idx]=acc>0.f?acc:0.f;
}
__global__ void k_hge(const int* dflag,const float* eags_h,const float* eags_t,
                      const void* W_re,const void* b_re,float* hge_h,float* hge_t){
  int idx = blockIdx.x*blockDim.x + threadIdx.x;
  if(idx>=G_*128) return;
  int side=blockIdx.y;
  const float* eags = side? eags_t : eags_h;
  float* hge = side? hge_t : hge_h;
  if(*dflag) hge_body<float>(idx,eags,W_re,b_re,hge);
  else       hge_body<bf16 >(idx,eags,W_re,b_re,hge);
}

// ---------------- per-node alphas for stage A (both sides via grid.y) ----------------
__global__ void k_node_alpha1(const int* dflag,const void* x_h,const void* x_t,
                              const float* __restrict__ cva,const float* __restrict__ cvb,
                              float* a1s_h,float* a1d_h,float* a1s_t,float* a1d_t){
  int i = blockIdx.x*blockDim.x + threadIdx.x;
  if(i>=N_) return;
  int side=blockIdx.y;
  const void* X = side? x_t : x_h;
  float* oa = side? a1s_t : a1s_h;
  float* ob = side? a1d_t : a1d_h;
  float a0=0,a1=0,b0=0,b1=0;
  if(*dflag){
    const float* x=(const float*)X + (size_t)i*64;
    for(int k=0;k<64;k++){ float v=x[k]; a0+=v*cva[k]; a1+=v*cva[64+k]; b0+=v*cvb[k]; b1+=v*cvb[64+k]; }
  } else {
    const bf16* x=(const bf16*)X + (size_t)i*64;
    for(int k=0;k<64;k++){ float v=b2f(x[k]); a0+=v*cva[k]; a1+=v*cva[64+k]; b0+=v*cvb[k]; b1+=v*cvb[64+k]; }
  }
  oa[i*2]=a0; oa[i*2+1]=a1; ob[i*2]=b0; ob[i*2+1]=b1;
}

// ---------------- stage-A edge alpha (with edge attr), CSR-ordered writes ----------------
__global__ void k_edge_alpha1(const int* dflag,
                              const float* a1s_h,const float* a1d_h,
                              const float* a1s_t,const float* a1d_t,
                              const int* ei_h,const int* ei_t,
                              const void* eat_h,const void* eat_t,
                              const float* __restrict__ vedge,
                              const float* lae_h,const float* lae_t,
                              const int* pos0,const int* pos1,
                              float* alpha_h,float* alpha_t){
  __shared__ float sv[128];
  int t = threadIdx.x;
  if(t<128) sv[t]=vedge[t];
  __syncthreads();
  int side=blockIdx.y;
  const float* asrc = side? a1s_t : a1s_h;
  const float* adst = side? a1d_t : a1d_h;
  const int* srcI = side? ei_t : ei_h;
  const int* dstI = srcI + E_;
  const void* eattr = side? eat_t : eat_h;
  const float* loopae = side? lae_t : lae_h;
  const int* pos = side? pos1 : pos0;
  float* alpha = side? alpha_t : alpha_h;
  int e = blockIdx.x*blockDim.x + t;
  if(e>=E_+N_) return;
  int s,d; float ae0=0.f, ae1=0.f;
  if(e<E_){
    s=srcI[e]; d=dstI[e];
    if(*dflag){
      const float4* row=(const float4*)((const float*)eattr + (size_t)e*64);
      #pragma unroll
      for(int k=0;k<16;k++){
        float4 v=row[k];
        ae0 += v.x*sv[4*k]   + v.y*sv[4*k+1]   + v.z*sv[4*k+2]   + v.w*sv[4*k+3];
        ae1 += v.x*sv[64+4*k]+ v.y*sv[64+4*k+1]+ v.z*sv[64+4*k+2]+ v.w*sv[64+4*k+3];
      }
    } else {
      const uint4* row=(const uint4*)((const bf16*)eattr + (size_t)e*64);
      #pragma unroll
      for(int k=0;k<8;k++){
        uint4 u=row[k];
        float f0=bfu(u.x&0xffffu), f1=bfu(u.x>>16), f2=bfu(u.y&0xffffu), f3=bfu(u.y>>16);
        float f4=bfu(u.z&0xffffu), f5=bfu(u.z>>16), f6=bfu(u.w&0xffffu), f7=bfu(u.w>>16);
        ae0 += f0*sv[8*k]+f1*sv[8*k+1]+f2*sv[8*k+2]+f3*sv[8*k+3]
             + f4*sv[8*k+4]+f5*sv[8*k+5]+f6*sv[8*k+6]+f7*sv[8*k+7];
        ae1 += f0*sv[64+8*k]+f1*sv[64+8*k+1]+f2*sv[64+8*k+2]+f3*sv[64+8*k+3]
             + f4*sv[64+8*k+4]+f5*sv[64+8*k+5]+f6*sv[64+8*k+6]+f7*sv[64+8*k+7];
      }
    }
  } else {
    s=d=e-E_;
    ae0=loopae[0]; ae1=loopae[1];
  }
  float l0 = asrc[s*2]  +adst[d*2]  +ae0; l0 = l0>0.f? l0 : 0.2f*l0;
  float l1 = asrc[s*2+1]+adst[d*2+1]+ae1; l1 = l1>0.f? l1 : 0.2f*l1;
  float e0 = expf(fminf(l0,50.f));
  float e1 = expf(fminf(l1,50.f));
  size_t w = (e<E_)? (size_t)pos[e] : (size_t)e;   // loops stay at [E..E+N)
  *(float2*)&alpha[w*2] = make_float2(e0,e1);
}

// ---------------- stage-2 edge alphas (4 jobs via grid.y), CSR-ordered writes ----------------
__global__ void k_edge_alpha2(const float* ais_h,const float* aid_h,
                              const float* ais_t,const float* aid_t,
                              const float* abs_h,const float* abd_h,
                              const float* abs_t,const float* abd_t,
                              const int* ei_h,const int* ei_t,const int* bei,
                              const int* poss,
                              float* a_ih,float* a_it,float* a_bt,float* a_bh){
  int e = blockIdx.x*blockDim.x + threadIdx.x;
  if(e>=E_+N_) return;
  int y = blockIdx.y;
  const float *asrc,*adst; const int *srcI,*dstI; float* alpha;
  if(y==0){ asrc=ais_h; adst=aid_h; srcI=ei_h;    dstI=ei_h+E_;  alpha=a_ih; }
  else if(y==1){ asrc=ais_t; adst=aid_t; srcI=ei_t; dstI=ei_t+E_; alpha=a_it; }
  else if(y==2){ asrc=abs_h; adst=abd_t; srcI=bei;  dstI=bei+EBI; alpha=a_bt; }
  else { asrc=abs_t; adst=abd_h; srcI=bei+EBI; dstI=bei; alpha=a_bh; }
  const int* pos = poss + (size_t)y*E_;
  int s,d;
  if(e<E_){ s=srcI[e]; d=dstI[e]; } else { s=d=e-E_; }
  float l0 = asrc[s*2]  +adst[d*2];   l0 = l0>0.f? l0 : 0.2f*l0;
  float l1 = asrc[s*2+1]+adst[d*2+1]; l1 = l1>0.f? l1 : 0.2f*l1;
  float e0 = expf(fminf(l0,50.f));
  float e1 = expf(fminf(l1,50.f));
  size_t w = (e<E_)? (size_t)pos[e] : (size_t)e;
  *(float2*)&alpha[w*2] = make_float2(e0,e1);
}

// ---------------- stage-A gather: 16 dst/block, 16 thr/dst, 4 f/thr, both heads ----------------
__global__ __launch_bounds__(256) void k_gatherA(const int* dflag,
    const void* x_h,const void* x_t,
    const float* alpha_h,const float* alpha_t,
    const int* rp0,const int* src0,
    const int* rp1,const int* src1,
    float* C,float* D){
  int t=threadIdx.x, side=blockIdx.y;
  int d=blockIdx.x*16 + (t>>4);
  if(d>=N_) return;
  int f4=(t&15)*4;
  const void* X = side? x_t : x_h;
  const float* alpha = side? alpha_t : alpha_h;
  const int* rp  = side? rp1  : rp0;
  const int* src = side? src1 : src0;
  float* out = side? D : C;
  int f32=*dflag;
  int j0=rp[d], j1=rp[d+1];
  float acc0[4]={0,0,0,0}, acc1[4]={0,0,0,0};
  float ss0=0.f, ss1=0.f;
  int j=j0;
  for(; j+1<j1; j+=2){
    int s0=src[j], s1=src[j+1];
    float2 a0=*(const float2*)&alpha[(size_t)j*2];
    float2 a1=*(const float2*)&alpha[(size_t)(j+1)*2];
    float x0[4], x1[4];
    if(f32){
      float4 v0=*(const float4*)((const float*)X+(size_t)s0*64+f4);
      float4 v1=*(const float4*)((const float*)X+(size_t)s1*64+f4);
      x0[0]=v0.x; x0[1]=v0.y; x0[2]=v0.z; x0[3]=v0.w;
      x1[0]=v1.x; x1[1]=v1.y; x1[2]=v1.z; x1[3]=v1.w;
    } else {
      uint2 u0=*(const uint2*)((const bf16*)X+(size_t)s0*64+f4);
      uint2 u1=*(const uint2*)((const bf16*)X+(size_t)s1*64+f4);
      x0[0]=bfu(u0.x&0xffffu); x0[1]=bfu(u0.x>>16); x0[2]=bfu(u0.y&0xffffu); x0[3]=bfu(u0.y>>16);
      x1[0]=bfu(u1.x&0xffffu); x1[1]=bfu(u1.x>>16); x1[2]=bfu(u1.y&0xffffu); x1[3]=bfu(u1.y>>16);
    }
    #pragma unroll
    for(int c=0;c<4;c++){
      acc0[c] += x0[c]*a0.x + x1[c]*a1.x;
      acc1[c] += x0[c]*a0.y + x1[c]*a1.y;
    }
    ss0+=a0.x+a1.x; ss1+=a0.y+a1.y;
  }
  if(j<j1){
    int s0=src[j];
    float2 a0=*(const float2*)&alpha[(size_t)j*2];
    float x0[4];
    if(f32){
      float4 v0=*(const float4*)((const float*)X+(size_t)s0*64+f4);
      x0[0]=v0.x; x0[1]=v0.y; x0[2]=v0.z; x0[3]=v0.w;
    } else {
      uint2 u0=*(const uint2*)((const bf16*)X+(size_t)s0*64+f4);
      x0[0]=bfu(u0.x&0xffffu); x0[1]=bfu(u0.x>>16); x0[2]=bfu(u0.y&0xffffu); x0[3]=bfu(u0.y>>16);
    }
    #pragma unroll
    for(int c=0;c<4;c++){ acc0[c]+=x0[c]*a0.x; acc1[c]+=x0[c]*a0.y; }
    ss0+=a0.x; ss1+=a0.y;
  }
  { // self loop
    float2 a=*(const float2*)&alpha[((size_t)E_+d)*2];
    float xv[4];
    if(f32){
      float4 v=*(const float4*)((const float*)X+(size_t)d*64+f4);
      xv[0]=v.x; xv[1]=v.y; xv[2]=v.z; xv[3]=v.w;
    } else {
      uint2 u=*(const uint2*)((const bf16*)X+(size_t)d*64+f4);
      xv[0]=bfu(u.x&0xffffu); xv[1]=bfu(u.x>>16); xv[2]=bfu(u.y&0xffffu); xv[3]=bfu(u.y>>16);
    }
    #pragma unroll
    for(int c=0;c<4;c++){ acc0[c]+=xv[c]*a.x; acc1[c]+=xv[c]*a.y; }
    ss0+=a.x; ss1+=a.y;
  }
  float i0=1.f/(ss0+1e-16f), i1=1.f/(ss1+1e-16f);
  float4 o0 = make_float4(acc0[0]*i0,acc0[1]*i0,acc0[2]*i0,acc0[3]*i0);
  float4 o1 = make_float4(acc1[0]*i1,acc1[1]*i1,acc1[2]*i1,acc1[3]*i1);
  *(float4*)&out[(size_t)d*128+f4]    = o0;
  *(float4*)&out[(size_t)d*128+64+f4] = o1;
}

// per-head transform of stage-A accumulator + bias + ELU (register-tiled)
// grid: (ceil(N/64), half, side)
__global__ __launch_bounds__(256) void k_headelu(const int* dflag,
    const float* __restrict__ C,const float* __restrict__ D,
    const void* W, const void* bias, bf16* eh, bf16* et){
  __shared__ float sA[64*68];
  __shared__ float sW[64*68];
  __shared__ float sB[64];
  const int t = threadIdx.x;
  const int half = blockIdx.y;
  const int side = blockIdx.z;
  const int n0 = blockIdx.x*64;
  const int f32 = *dflag;
  const float* acc = side? D : C;
  bf16* out = side? et : eh;
  for(int i=t;i<4096;i+=256){
    int o=i>>6, k=i&63;
    float v = f32 ? ((const float*)W)[(size_t)(half*64+o)*64+k]
                  : b2f(((const bf16*)W)[(size_t)(half*64+o)*64+k]);
    int om = (o>>2) | ((o&3)<<4);
    sW[om*68+k] = v;
  }
  if(t<64) sB[t] = f32 ? ((const float*)bias)[half*64+t] : b2f(((const bf16*)bias)[half*64+t]);
  for(int i=t;i<1024;i+=256){
    int m=i>>4, k4=i&15;
    int n=n0+m;
    float4 v = make_float4(0.f,0.f,0.f,0.f);
    if(n<N_) v = *(const float4*)&acc[((size_t)(2*n+half))*64 + k4*4];
    *(float4*)&sA[m*68 + k4*4] = v;
  }
  __syncthreads();
  const int cg = t&15, rg = t>>4;
  float s[4][4];
  #pragma unroll
  for(int i=0;i<4;i++)
    #pragma unroll
    for(int j=0;j<4;j++) s[i][j]=0.f;
  #pragma unroll 4
  for(int k0=0;k0<64;k0+=4){
    float4 a[4], w[4];
    #pragma unroll
    for(int i=0;i<4;i++) a[i] = *(const float4*)&sA[(rg+16*i)*68 + k0];
    #pragma unroll
    for(int j=0;j<4;j++) w[j] = *(const float4*)&sW[(cg+16*j)*68 + k0];
    #pragma unroll
    for(int i=0;i<4;i++)
      #pragma unroll
      for(int j=0;j<4;j++)
        s[i][j] += a[i].x*w[j].x + a[i].y*w[j].y + a[i].z*w[j].z + a[i].w*w[j].w;
  }
  #pragma unroll
  for(int i=0;i<4;i++){
    int n = n0 + rg + 16*i;
    if(n>=N_) continue;
    union { bf16 h[4]; uint2 u; } pk;
    #pragma unroll
    for(int j=0;j<4;j++){
      float v = s[i][j] + sB[4*cg+j];
      v = v>0.f ? v : expf(v)-1.f;
      pk.h[j] = f2b(v);
    }
    *(uint2*)&out[((size_t)(2*n+half))*64 + 4*cg] = pk.u;
  }
}

// ---------------- fused: msgI/msgB GEMMs + 8 stage-2 alpha dots (per side) ----------------
__global__ __launch_bounds__(256) void k_msg_alpha(const int* dflag,
    const bf16* __restrict__ eh, const bf16* __restrict__ et,
    const void* W_i, const void* W_bs,
    const float* c_i_s,const float* c_i_d,const float* c_b_s,const float* c_b_d,
    bf16* msgI_h,bf16* msgI_t,bf16* msgB_h,bf16* msgB_t,
    float* ais_h,float* aid_h,float* abs_h,float* abd_h,
    float* ais_t,float* aid_t,float* abs_t,float* abd_t){
  __shared__ float sA[64*132];
  __shared__ float sW[64*68];
  __shared__ float scv[8*132];
  int t=threadIdx.x, side=blockIdx.y;
  int n0=blockIdx.x*64;
  const bf16* X = side? et : eh;
  bf16* msgI = side? msgI_t : msgI_h;
  bf16* msgB = side? msgB_t : msgB_h;
  float* ais = side? ais_t : ais_h;
  float* aid = side? aid_t : aid_h;
  float* ab_s = side? abs_t : abs_h;
  float* ab_d = side? abd_t : abd_h;
  int f32=*dflag;
  // stage A rows (bf16 -> f32), zero-fill OOB
  for(int i=t;i<512;i+=256){
    int m=i>>3, c16=(i&7)*16;
    int n=n0+m;
    float v[16];
    if(n<N_){
      uint4 u0=*(const uint4*)(X+(size_t)n*128+c16);
      uint4 u1=*(const uint4*)(X+(size_t)n*128+c16+8);
      v[0]=bfu(u0.x&0xffffu); v[1]=bfu(u0.x>>16); v[2]=bfu(u0.y&0xffffu); v[3]=bfu(u0.y>>16);
      v[4]=bfu(u0.z&0xffffu); v[5]=bfu(u0.z>>16); v[6]=bfu(u0.w&0xffffu); v[7]=bfu(u0.w>>16);
      v[8]=bfu(u1.x&0xffffu); v[9]=bfu(u1.x>>16); v[10]=bfu(u1.y&0xffffu); v[11]=bfu(u1.y>>16);
      v[12]=bfu(u1.z&0xffffu); v[13]=bfu(u1.z>>16); v[14]=bfu(u1.w&0xffffu); v[15]=bfu(u1.w>>16);
    } else {
      #pragma unroll
      for(int q=0;q<16;q++) v[q]=0.f;
    }
    #pragma unroll
    for(int q=0;q<16;q++) sA[m*132+c16+q]=v[q];
  }
  // stage combined attention vectors
  for(int i=t;i<1024;i+=256){
    int v=i>>7, k=i&127;
    const float* s = (v<2)? c_i_s : (v<4)? c_i_d : (v<6)? c_b_s : c_b_d;
    scv[v*132+k] = s[(v&1)*128+k];
  }
  __syncthreads();
  // 8 alpha dots per row
  #pragma unroll
  for(int it=0;it<2;it++){
    int task=t+it*256;
    int row=task>>3, v=task&7;
    int n=n0+row;
    float acc=0.f;
    for(int k=0;k<128;k++) acc += sA[row*132+k]*scv[v*132+k];
    if(n<N_){
      float* o = (v<2)? ais : (v<4)? aid : (v<6)? ab_s : ab_d;
      o[(size_t)n*2+(v&1)]=acc;
    }
  }
  // two O=64 GEMMs sharing sA
  const int cg=t&15, rg=t>>4;
  for(int chunk=0;chunk<2;chunk++){
    const void* W = chunk? W_bs : W_i;
    bf16* out = chunk? msgB : msgI;
    float s[4][4];
    #pragma unroll
    for(int i=0;i<4;i++)
      #pragma unroll
      for(int j=0;j<4;j++) s[i][j]=0.f;
    for(int kc=0;kc<128;kc+=64){
      __syncthreads();
      for(int i=t;i<4096;i+=256){
        int o=i>>6,k=i&63;
        float v = f32? ((const float*)W)[(size_t)o*128+kc+k] : b2f(((const bf16*)W)[(size_t)o*128+kc+k]);
        int om=(o>>2)|((o&3)<<4);
        sW[om*68+k]=v;
      }
      __syncthreads();
      #pragma unroll 4
      for(int k0=0;k0<64;k0+=4){
        float4 a[4], w[4];
        #pragma unroll
        for(int i=0;i<4;i++) a[i] = *(const float4*)&sA[(rg+16*i)*132 + kc + k0];
        #pragma unroll
        for(int j=0;j<4;j++) w[j] = *(const float4*)&sW[(cg+16*j)*68 + k0];
        #pragma unroll
        for(int i=0;i<4;i++)
          #pragma unroll
          for(int j=0;j<4;j++)
            s[i][j] += a[i].x*w[j].x + a[i].y*w[j].y + a[i].z*w[j].z + a[i].w*w[j].w;
      }
    }
    #pragma unroll
    for(int i=0;i<4;i++){
      int n = n0 + rg + 16*i;
      if(n>=N_) continue;
      union { bf16 h[4]; uint2 u; } pk;
      #pragma unroll
      for(int j=0;j<4;j++) pk.h[j]=f2b(s[i][j]);
      *(uint2*)&out[(size_t)n*64 + 4*cg] = pk.u;
    }
  }
}

// ---------------- fused stage-2 gather + rep + z/score dots ----------------
// grid: (N/8, side); 256 thr = 8 dst x 32 thr (16 per half), 4 ch/thr
__global__ __launch_bounds__(256) void k_gather_rep(const int* dflag,
    const bf16* msgI_h,const bf16* msgI_t,const bf16* msgB_h,const bf16* msgB_t,
    const float* a_ih,const float* a_it,const float* a_bt,const float* a_bh,
    const int* rp0,const int* src0,
    const int* rp1,const int* src1,
    const int* rp2,const int* src2,
    const int* rp3,const int* src3,
    const void* b_intra,const void* b_inter,
    const void* W_rel,const void* b_rel,const void* W_root,
    float* h_rep,float* t_rep,
    float* z_h,float* z_t,float* sc_h,float* sc_t){
  int t=threadIdx.x, side=blockIdx.y;
  int d=blockIdx.x*8 + (t>>5);
  if(d>=N_) return;
  int g=t&31, half=g>>4, l=g&15, ch64=l*4, hh=l>>3;
  const bf16* msg; const float* alpha; const int *rp,*src; const void* bias;
  float *rep,*z,*sc;
  if(side==0){
    rep=h_rep; z=z_h; sc=sc_h;
    if(half==0){ msg=msgI_h; alpha=a_ih; rp=rp0; src=src0; bias=b_intra; }
    else       { msg=msgB_t; alpha=a_bh; rp=rp3; src=src3; bias=b_inter; }
  } else {
    rep=t_rep; z=z_t; sc=sc_t;
    if(half==0){ msg=msgI_t; alpha=a_it; rp=rp1; src=src1; bias=b_intra; }
    else       { msg=msgB_h; alpha=a_bt; rp=rp2; src=src2; bias=b_inter; }
  }
  int f32=*dflag;
  int j0=rp[d], j1=rp[d+1];
  float acc[4]={0,0,0,0};
  float ss=0.f;
  int j=j0;
  for(; j+1<j1; j+=2){
    int s0=src[j], s1=src[j+1];
    float a0=alpha[(size_t)j*2+hh];
    float a1=alpha[(size_t)(j+1)*2+hh];
    uint2 m0=*(const uint2*)&msg[(size_t)s0*64+ch64];
    uint2 m1=*(const uint2*)&msg[(size_t)s1*64+ch64];
    acc[0]+=bfu(m0.x&0xffffu)*a0 + bfu(m1.x&0xffffu)*a1;
    acc[1]+=bfu(m0.x>>16)*a0     + bfu(m1.x>>16)*a1;
    acc[2]+=bfu(m0.y&0xffffu)*a0 + bfu(m1.y&0xffffu)*a1;
    acc[3]+=bfu(m0.y>>16)*a0     + bfu(m1.y>>16)*a1;
    ss+=a0+a1;
  }
  if(j<j1){
    int s0=src[j];
    float a0=alpha[(size_t)j*2+hh];
    uint2 m0=*(const uint2*)&msg[(size_t)s0*64+ch64];
    acc[0]+=bfu(m0.x&0xffffu)*a0;
    acc[1]+=bfu(m0.x>>16)*a0;
    acc[2]+=bfu(m0.y&0xffffu)*a0;
    acc[3]+=bfu(m0.y>>16)*a0;
    ss+=a0;
  }
  { // self loop
    float a=alpha[((size_t)E_+d)*2+hh];
    uint2 m=*(const uint2*)&msg[(size_t)d*64+ch64];
    acc[0]+=bfu(m.x&0xffffu)*a;
    acc[1]+=bfu(m.x>>16)*a;
    acc[2]+=bfu(m.y&0xffffu)*a;
    acc[3]+=bfu(m.y>>16)*a;
    ss+=a;
  }
  float inv=1.f/(ss+1e-16f);
  float repv[4];
  #pragma unroll
  for(int c=0;c<4;c++){
    float b = f32? ((const float*)bias)[ch64+c] : b2f(((const bf16*)bias)[ch64+c]);
    repv[c]=acc[c]*inv+b;
  }
  *(float4*)&rep[(size_t)d*128 + half*64 + ch64] = make_float4(repv[0],repv[1],repv[2],repv[3]);
  // z/score partial dots over this thread's 4 channels
  float pz=0.f, pr=0.f;
  #pragma unroll
  for(int c=0;c<4;c++){
    int ch = half*64+ch64+c;
    float wrel = f32? ((const float*)W_rel)[ch] : b2f(((const bf16*)W_rel)[ch]);
    float wroot= f32? ((const float*)W_root)[ch]: b2f(((const bf16*)W_root)[ch]);
    pz += repv[c]*wrel; pr += repv[c]*wroot;
  }
  #pragma unroll
  for(int m=1;m<=16;m<<=1){ pz+=__shfl_xor(pz,m); pr+=__shfl_xor(pr,m); }
  if(g==0){
    float br = f32? ((const float*)b_rel)[0] : b2f(((const bf16*)b_rel)[0]);
    z[d]=pz; sc[d]=pr+br;
  }
}

// score[d] += sum of z over incoming real edges (CSR, no atomics)
__global__ void k_score_gather(const float* z_h,const float* z_t,
    const int* rp0,const int* src0,const int* rp1,const int* src1,
    float* sc_h,float* sc_t){
  int i = blockIdx.x*blockDim.x + threadIdx.x;
  if(i>=N_) return;
  int side=blockIdx.y;
  const float* z = side? z_t : z_h;
  const int* rp = side? rp1 : rp0;
  const int* sr = side? src1 : src0;
  float* sc = side? sc_t : sc_h;
  float a=0.f;
  for(int j=rp[i];j<rp[i+1];j++) a += z[sr[j]];
  sc[i]+=a;
}

// ---------------- fused SAG readout + graph LayerNorm ----------------
__global__ __launch_bounds__(128) void k_finalize(const int* dflag,
    const float* __restrict__ h_rep,const float* __restrict__ t_rep,
    const float* __restrict__ sc_h,const float* __restrict__ sc_t,
    const int* ns_h,const int* ne_h,const int* ns_t,const int* ne_t,
    const float* __restrict__ hge_h,const float* __restrict__ hge_t,
    const void* lnw,const void* lnb,
    void* out,size_t o_hg,size_t o_tg,size_t o_hx,size_t o_tx){
  int g=blockIdx.x, side=blockIdx.y, tid=threadIdx.x;
  const float* rep = side? t_rep : h_rep;
  const float* sc  = side? sc_t  : sc_h;
  const float* hge = side? hge_t : hge_h;
  int s = side? ns_t[g] : ns_h[g];
  int e = side? ne_t[g] : ne_h[g];
  size_t og = side? o_tg : o_hg;
  size_t ox = side? o_tx : o_hx;
  __shared__ float red[128];
  float m=-1e30f;
  for(int n=s+tid;n<e;n+=128) m=fmaxf(m,sc[n]);
  red[tid]=m; __syncthreads();
  for(int w=64;w>0;w>>=1){ if(tid<w) red[tid]=fmaxf(red[tid],red[tid+w]); __syncthreads(); }
  float M=red[0]; __syncthreads();
  float den=0.f;
  for(int n=s+tid;n<e;n+=128) den += expf(sc[n]-M);
  red[tid]=den; __syncthreads();
  for(int w=64;w>0;w>>=1){ if(tid<w) red[tid]+=red[tid+w]; __syncthreads(); }
  den=red[0]; __syncthreads();
  float sm=0.f,sq=0.f;
  for(int n=s;n<e;n++){ float v=rep[(size_t)n*128+tid]; sm+=v; sq+=v*v; }
  red[tid]=sm; __syncthreads();
  for(int w=64;w>0;w>>=1){ if(tid<w) red[tid]+=red[tid+w]; __syncthreads(); }
  float S=red[0]; __syncthreads();
  red[tid]=sq; __syncthreads();
  for(int w=64;w>0;w>>=1){ if(tid<w) red[tid]+=red[tid+w]; __syncthreads(); }
  float SQ=red[0];
  float cntf=(float)(e-s);
  float norm=(cntf>1.f?cntf:1.f)*128.f;
  float mean=S/norm;
  float var=SQ/norm-mean*mean; var=var>0.f?var:0.f;
  float inv=rsqrtf(var+1e-5f);
  int f32=*dflag;
  float wf,bb;
  if(f32){ wf=((const float*)lnw)[tid]; bb=((const float*)lnb)[tid]; }
  else   { wf=b2f(((const bf16*)lnw)[tid]); bb=b2f(((const bf16*)lnb)[tid]); }
  float acc=0.f;
  for(int n=s;n<e;n++){
    float v=rep[(size_t)n*128+tid];
    acc += v*expf(sc[n]-M);
    float lv=(v-mean)*inv*wf+bb;
    lv = lv>0.f? lv : 0.f;
    if(f32) ((float*)out)[ox+(size_t)n*128+tid]=lv;
    else    ((bf16 *)out)[ox+(size_t)n*128+tid]=f2b(lv);
  }
  float v = acc/(den+1e-16f) + hge[(size_t)g*128+tid];
  if(f32) ((float*)out)[og+(size_t)g*128+tid]=v;
  else    ((bf16 *)out)[og+(size_t)g*128+tid]=f2b(v);
}

// ---------------- final relu(ea) dense: out = relu(eat @ W_lu^T + b_lu), both sides ----------------
__global__ __launch_bounds__(256) void k_ea_final(const int* dflag,
    const void* eat_h,const void* eat_t,
    const void* W,const void* bias,void* out,size_t off_h,size_t off_t){
  __shared__ float sA[64*68];
  __shared__ float sW[64*68];
  __shared__ float sB[64];
  const int t=threadIdx.x;
  const int side=blockIdx.y;
  const int n0=blockIdx.x*64;
  const int f32=*dflag;
  const void* A = side? eat_t : eat_h;
  size_t outOff = side? off_t : off_h;
  if(t<64) sB[t] = f32? ((const float*)bias)[t] : b2f(((const bf16*)bias)[t]);
  for(int i=t;i<4096;i+=256){
    int o=i>>6, k=i&63;
    float v = f32 ? ((const float*)W)[(size_t)o*64+k] : b2f(((const bf16*)W)[(size_t)o*64+k]);
    int om=(o>>2)|((o&3)<<4);
    sW[om*68+k]=v;
  }
  if(f32){
    for(int i=t;i<1024;i+=256){
      int m=i>>4, k4=(i&15)*4; int n=n0+m;
      float4 v = *(const float4*)((const float*)A + (size_t)n*64 + k4);
      *(float4*)&sA[m*68+k4] = v;
    }
  } else {
    for(int i=t;i<512;i+=256){
      int m=i>>3, k8=(i&7)*8; int n=n0+m;
      uint4 u = *(const uint4*)((const bf16*)A + (size_t)n*64 + k8);
      float4 v0, v1;
      v0.x=bfu(u.x&0xffffu); v0.y=bfu(u.x>>16); v0.z=bfu(u.y&0xffffu); v0.w=bfu(u.y>>16);
      v1.x=bfu(u.z&0xffffu); v1.y=bfu(u.z>>16); v1.z=bfu(u.w&0xffffu); v1.w=bfu(u.w>>16);
      *(float4*)&sA[m*68+k8]   = v0;
      *(float4*)&sA[m*68+k8+4] = v1;
    }
  }
  __syncthreads();
  const int cg=t&15, rg=t>>4;
  float s[4][4];
  #pragma unroll
  for(int i=0;i<4;i++)
    #pragma unroll
    for(int j=0;j<4;j++) s[i][j]=0.f;
  #pragma unroll 4
  for(int k0=0;k0<64;k0+=4){
    float4 a[4], w[4];
    #pragma unroll
    for(int i=0;i<4;i++) a[i] = *(const float4*)&sA[(rg+16*i)*68 + k0];
    #pragma unroll
    for(int j=0;j<4;j++) w[j] = *(const float4*)&sW[(cg+16*j)*68 + k0];
    #pragma unroll
    for(int i=0;i<4;i++)
      #pragma unroll
      for(int j=0;j<4;j++)
        s[i][j] += a[i].x*w[j].x + a[i].y*w[j].y + a[i].z*w[j].z + a[i].w*w[j].w;
  }
  #pragma unroll
  for(int i=0;i<4;i++){
    int n = n0 + rg + 16*i;
    float vv[4];
    #pragma unroll
    for(int j=0;j<4;j++){
      float v = s[i][j] + sB[4*cg+j];
      vv[j] = v>0.f? v : 0.f;
    }
    if(f32){
      float4 v4 = make_float4(vv[0],vv[1],vv[2],vv[3]);
      *(float4*)((float*)out + outOff + (size_t)n*64 + 4*cg) = v4;
    } else {
      union { bf16 h[4]; uint2 u; } pk;
      #pragma unroll
      for(int j=0;j<4;j++) pk.h[j]=f2b(vv[j]);
      *(uint2*)((bf16*)out + outOff + (size_t)n*64 + 4*cg) = pk.u;
    }
  }
}

extern "C" void kernel_launch(void* const* d_in, const int* in_sizes, int n_in,
                              void* d_out, int out_size, void* d_ws, size_t ws_size,
                              hipStream_t stream) {
  const void* x_h      = d_in[0];
  const void* x_t      = d_in[1];
  const void* eat_h    = d_in[2];
  const void* eat_t    = d_in[3];
  const int*  ei_h     = (const int*)d_in[4];
  const int*  ei_t     = (const int*)d_in[5];
  const int*  bei      = (const int*)d_in[6];
  const int*  batch_h  = (const int*)d_in[7];
  const int*  batch_t  = (const int*)d_in[8];
  const int*  ebat_h   = (const int*)d_in[9];
  const int*  ebat_t   = (const int*)d_in[10];
  const void* W_fc     = d_in[11];
  const void* a_s_fc   = d_in[12];
  const void* a_d_fc   = d_in[13];
  const void* W_e      = d_in[14];
  const void* a_e      = d_in[15];
  const void* b_fc     = d_in[16];
  const void* W_lu     = d_in[17];
  const void* b_lu     = d_in[18];
  const void* W_i      = d_in[19];
  const void* a_s_i    = d_in[20];
  const void* a_d_i    = d_in[21];
  const void* b_intra  = d_in[22];
  const void* W_bs     = d_in[23];
  const void* W_bd     = d_in[24];
  const void* a_s_b    = d_in[25];
  const void* a_d_b    = d_in[26];
  const void* b_inter  = d_in[27];
  const void* W_rel    = d_in[28];
  const void* b_rel    = d_in[29];
  const void* W_root   = d_in[30];
  const void* ln_w     = d_in[31];
  const void* ln_b     = d_in[32];
  const void* W_re     = d_in[33];
  const void* b_re     = d_in[34];

  // output element offsets (elements, in output dtype)
  const size_t o_hx  = 0;
  const size_t o_eah = (size_t)N_*128;
  const size_t o_tx  = o_eah + (size_t)E_*64;
  const size_t o_eat = o_tx  + (size_t)N_*128;
  const size_t o_hg  = o_eat + (size_t)E_*64;
  const size_t o_tg  = o_hg  + (size_t)G_*128;

  // ---- d_out as mid-pipeline scratch (bf16-indexed; all dead before final writes) ----
  bf16* eh   = (bf16*)d_out + o_hx;
  bf16* et   = (bf16*)d_out + o_tx;
  bf16* msgI_h = (bf16*)d_out + o_eah;
  bf16* msgI_t = msgI_h + (size_t)N_*64;
  bf16* msgB_h = msgI_h + (size_t)2*N_*64;
  bf16* msgB_t = msgI_h + (size_t)3*N_*64;
  float* areg  = (float*)((bf16*)d_out + o_eat);
  float* alpha1_h  = areg;
  float* alpha1_t  = areg + (size_t)(E_+N_)*2;
  float* alpha2_ih = areg + (size_t)2*(E_+N_)*2;
  float* alpha2_it = areg + (size_t)3*(E_+N_)*2;
  float* alpha2_bt = alpha1_h;   // alias: alpha1 dead before stage-2 bipartite
  float* alpha2_bh = alpha1_t;
  int* csr_base = (int*)(areg + (size_t)4*(E_+N_)*2);
  int* poss = csr_base;                     // 4 x E : pos[e] (CSR slot of edge e)
  int* srcs = csr_base + (size_t)4*E_;      // 4 x E : src in CSR order
  int* pos0 = poss;                 int* pos1 = poss + (size_t)E_;
  int* src0 = srcs;                 int* src1 = srcs + (size_t)E_;
  int* src2 = srcs + (size_t)2*E_;  int* src3 = srcs + (size_t)3*E_;

  // ---------------- workspace arena ----------------
  char* p = (char*)d_ws;
  size_t off = 0;
  auto alloc = [&](size_t bytes)->char*{
    char* r = p + off; off += (bytes + 255) & ~(size_t)255; return r;
  };
  int* dflag=(int*)alloc(256);
  int* es_h = (int*)alloc(G_*4); int* ee_h = (int*)alloc(G_*4);
  int* es_t = (int*)alloc(G_*4); int* ee_t = (int*)alloc(G_*4);
  int* ns_h = (int*)alloc(G_*4); int* ne_h = (int*)alloc(G_*4);
  int* ns_t = (int*)alloc(G_*4); int* ne_t = (int*)alloc(G_*4);
  float* sumea_h = (float*)alloc(64*4);
  float* sumea_t = (float*)alloc(64*4);
  float* c_fc_s=(float*)alloc(128*4); float* c_fc_d=(float*)alloc(128*4);
  float* v_edge=(float*)alloc(128*4);
  float* c_i_s=(float*)alloc(256*4);  float* c_i_d=(float*)alloc(256*4);
  float* c_b_s=(float*)alloc(256*4);  float* c_b_d=(float*)alloc(256*4);
  float* lae_h=(float*)alloc(2*4);    float* lae_t=(float*)alloc(2*4);
  int* cnt    = (int*)alloc((size_t)4*N_*4);
  int* cur    = (int*)alloc((size_t)4*N_*4);
  int* rowptr = (int*)alloc((size_t)4*NP1*4);
  int* part   = (int*)alloc((size_t)4*SCAN_NB*4);
  float* a1s_h=(float*)alloc((size_t)N_*2*4); float* a1d_h=(float*)alloc((size_t)N_*2*4);
  float* a1s_t=(float*)alloc((size_t)N_*2*4); float* a1d_t=(float*)alloc((size_t)N_*2*4);
  float* ais_h=(float*)alloc((size_t)N_*2*4); float* aid_h=(float*)alloc((size_t)N_*2*4);
  float* ais_t=(float*)alloc((size_t)N_*2*4); float* aid_t=(float*)alloc((size_t)N_*2*4);
  float* abs_h=(float*)alloc((size_t)N_*2*4); float* abd_h=(float*)alloc((size_t)N_*2*4);
  float* abs_t=(float*)alloc((size_t)N_*2*4); float* abd_t=(float*)alloc((size_t)N_*2*4);
  float* z_h=(float*)alloc((size_t)N_*4); float* z_t=(float*)alloc((size_t)N_*4);
  float* sc_h=(float*)alloc((size_t)N_*4); float* sc_t=(float*)alloc((size_t)N_*4);
  float* gsum_h=(float*)alloc((size_t)G_*64*4); float* gsum_t=(float*)alloc((size_t)G_*64*4);
  float* eags_h=(float*)alloc((size_t)G_*64*4); float* eags_t=(float*)alloc((size_t)G_*64*4);
  float* hge_h =(float*)alloc((size_t)G_*128*4); float* hge_t =(float*)alloc((size_t)G_*128*4);
  float* C = (float*)alloc((size_t)N_*128*4);   // stage-A acc (h), then t_rep
  float* D = (float*)alloc((size_t)N_*128*4);   // stage-A acc (t), then h_rep
  float* t_rep = C;
  float* h_rep = D;

  int* rp0 = rowptr;                  int* rp1 = rowptr + (size_t)NP1;
  int* rp2 = rowptr + (size_t)2*NP1;  int* rp3 = rowptr + (size_t)3*NP1;

  auto cdiv=[](long a, long b){ return (int)((a+b-1)/b); };

  // ---------------- phase 0: probe, zero, setup ----------------
  k_detect<<<1,256,0,stream>>>(x_h, dflag);
  hipMemsetAsync(es_h, 0, (size_t)G_*4*8, stream);
  hipMemsetAsync(sumea_h, 0, 512, stream);
  hipMemsetAsync(cnt, 0, (size_t)4*N_*4, stream);

  k_combine<<<6,256,0,stream>>>(dflag, W_fc,a_s_fc,a_d_fc, W_e,a_e, W_i,a_s_i,a_d_i,
                                W_bs,W_bd,a_s_b,a_d_b,
                                c_fc_s,c_fc_d,v_edge,c_i_s,c_i_d,c_b_s,c_b_d);
  k_ranges4<<<dim3(cdiv(E_,256),4),256,0,stream>>>(ebat_h,ebat_t,batch_h,batch_t,
                                es_h,ee_h,es_t,ee_t,ns_h,ne_h,ns_t,ne_t);

  // ---------------- CSR build ----------------
  k_hist4<<<dim3(cdiv(E_,256),4),256,0,stream>>>(ei_h, ei_t, bei, cnt);
  k_scan1<<<dim3(SCAN_NB,4),256,0,stream>>>(cnt, rowptr, part);
  k_scan2<<<4,32,0,stream>>>(part, rowptr);
  k_scan3<<<dim3(SCAN_NB,4),256,0,stream>>>(rowptr, part, cur);
  k_fill4<<<dim3(cdiv(E_,256),4),256,0,stream>>>(ei_h, ei_t, bei, cur, poss, srcs);

  // ---------------- edge-graph pooling path ----------------
  k_graph_easum<<<dim3(G_,2),256,0,stream>>>(dflag, eat_h,eat_t, es_h,ee_h,es_t,ee_t,
                                gsum_h,gsum_t, sumea_h,sumea_t);
  k_loopae2<<<2,64,0,stream>>>(sumea_h, sumea_t, v_edge, lae_h, lae_t, 1.f/(float)E_);
  k_ea_gs<<<dim3(cdiv(G_*64,256),2),256,0,stream>>>(dflag, gsum_h,gsum_t,
                                es_h,ee_h,es_t,ee_t, W_lu, b_lu, eags_h, eags_t);
  k_hge<<<dim3(cdiv(G_*128,256),2),256,0,stream>>>(dflag, eags_h, eags_t, W_re, b_re, hge_h, hge_t);

  // ---------------- stage A: feature GATConv ----------------
  k_node_alpha1<<<dim3(cdiv(N_,256),2),256,0,stream>>>(dflag, x_h, x_t, c_fc_s, c_fc_d,
                                a1s_h, a1d_h, a1s_t, a1d_t);
  k_edge_alpha1<<<dim3(cdiv(E_+N_,256),2),256,0,stream>>>(dflag, a1s_h,a1d_h,a1s_t,a1d_t,
                                ei_h, ei_t, eat_h, eat_t, v_edge, lae_h, lae_t,
                                pos0, pos1, alpha1_h, alpha1_t);
  k_gatherA<<<dim3(cdiv(N_,16),2),256,0,stream>>>(dflag, x_h, x_t, alpha1_h, alpha1_t,
                                rp0, src0, rp1, src1, C, D);
  k_headelu<<<dim3(cdiv(N_,64),2,2),256,0,stream>>>(dflag, C, D, W_fc, b_fc, eh, et);

  // ---------------- stage 2: fused message transforms + alphas ----------------
  k_msg_alpha<<<dim3(cdiv(N_,64),2),256,0,stream>>>(dflag, eh, et, W_i, W_bs,
                                c_i_s, c_i_d, c_b_s, c_b_d,
                                msgI_h, msgI_t, msgB_h, msgB_t,
                                ais_h, aid_h, abs_h, abd_h,
                                ais_t, aid_t, abs_t, abd_t);
  k_edge_alpha2<<<dim3(cdiv(E_+N_,256),4),256,0,stream>>>(ais_h,aid_h,ais_t,aid_t,
                                abs_h,abd_h,abs_t,abd_t, ei_h, ei_t, bei, poss,
                                alpha2_ih, alpha2_it, alpha2_bt, alpha2_bh);

  // ---------------- stage 2: gather + rep + z/score ----------------
  k_gather_rep<<<dim3(cdiv(N_,8),2),256,0,stream>>>(dflag,
                                msgI_h, msgI_t, msgB_h, msgB_t,
                                alpha2_ih, alpha2_it, alpha2_bt, alpha2_bh,
                                rp0, src0, rp1, src1, rp2, src2, rp3, src3,
                                b_intra, b_inter, W_rel, b_rel, W_root,
                                h_rep, t_rep, z_h, z_t, sc_h, sc_t);
  k_score_gather<<<dim3(cdiv(N_,256),2),256,0,stream>>>(z_h, z_t, rp0, src0, rp1, src1, sc_h, sc_t);

  // ---------------- fused readout + LN ----------------
  k_finalize<<<dim3(G_,2),128,0,stream>>>(dflag, h_rep, t_rep, sc_h, sc_t,
                                ns_h, ne_h, ns_t, ne_t, hge_h, hge_t,
                                ln_w, ln_b, d_out, o_hg, o_tg, o_hx, o_tx);

  // ---------------- final: relu(ea) outputs ----------------
  k_ea_final<<<dim3(E_/64,2),256,0,stream>>>(dflag, eat_h, eat_t, W_lu, b_lu,
                                d_out, o_eah, o_eat);

  (void)in_sizes; (void)n_in; (void)out_size; (void)ws_size;
}